// Round 1
// baseline (2257.684 us; speedup 1.0000x reference)
//
#include <hip/hip_runtime.h>
#include <math.h>

#define B_    4
#define K_    2048
#define D_    1024
#define H_    16
#define HD_   64
#define NCTX_ 1024

// ---------------------------------------------------------------------------
// Kernel 1: partition scan. One block (256 thr) per batch.
// pos[b][k]  = destination row of token k (ctx rows 0..1023 then tgt rows)
// ipos[b][r] = source token of destination row r
// Handles is_context stored as bool(1B), int32(4B) or int64(8B).
// ---------------------------------------------------------------------------
__global__ __launch_bounds__(256) void partition_kernel(
    const unsigned char* __restrict__ isctx, int* __restrict__ pos,
    int* __restrict__ ipos) {
  const int b = blockIdx.x;
  const int tid = threadIdx.x;
  const int wid = tid >> 6, lane = tid & 63;
  __shared__ int csum[4];
  __shared__ int waveTot[4];
  __shared__ int strideSh;

  // --- sniff element stride: count nonzero bytes in first 8192 bytes ---
  int cnt = 0;
  for (int i = 0; i < 32; ++i) cnt += (isctx[tid * 32 + i] != 0);
  for (int off = 32; off; off >>= 1) cnt += __shfl_down(cnt, off, 64);
  if (lane == 0) csum[wid] = cnt;
  __syncthreads();
  if (tid == 0) {
    int t = csum[0] + csum[1] + csum[2] + csum[3];
    strideSh = (t > 2048) ? 1 : ((t > 768) ? 4 : 8);  // bool=4096, i32=1024, i64~512
  }
  __syncthreads();
  const int stride = strideSh;

  // --- per-batch prefix sum over 2048 flags, 8 per thread ---
  const unsigned char* base = isctx + (size_t)b * K_ * stride;
  int f[8];
  int s = 0;
  for (int i = 0; i < 8; ++i) {
    f[i] = base[(size_t)(tid * 8 + i) * stride] != 0;
    s += f[i];
  }
  int inc = s;
  for (int off = 1; off < 64; off <<= 1) {
    int v = __shfl_up(inc, off, 64);
    if (lane >= off) inc += v;
  }
  if (lane == 63) waveTot[wid] = inc;
  __syncthreads();
  int wOff = 0;
  for (int w = 0; w < wid; ++w) wOff += waveTot[w];
  int run = wOff + inc - s;  // exclusive count of ctx before element tid*8
  for (int i = 0; i < 8; ++i) {
    int k = tid * 8 + i;
    int p;
    if (f[i]) {
      p = run;
      run++;
    } else {
      p = NCTX_ + k - run;
    }
    pos[b * K_ + k] = p;
    ipos[b * K_ + p] = k;
  }
}

// ---------------------------------------------------------------------------
// Kernel 2: RoPE + permute-gather. One block per destination row.
// tok[b][r][:] = rope(x[b][ipos[b][r]][:])
// ---------------------------------------------------------------------------
__global__ __launch_bounds__(256) void rope_kernel(
    const float* __restrict__ x, const float* __restrict__ coords,
    const float* __restrict__ cache, const int* __restrict__ ipos,
    float* __restrict__ tok) {
  const int row = blockIdx.x;  // 0..B*K-1
  const int b = row >> 11;
  const int r = row & (K_ - 1);
  const int k = ipos[row];
  const int t = threadIdx.x;  // 256 threads, 4 floats each

  const float cy = coords[(size_t)(b * K_ + k) * 2 + 0];
  const float cx = coords[(size_t)(b * K_ + k) * 2 + 1];
  // replicate reference op order exactly: (c / 224) * 1023, clip, trunc
  const int ypos = (int)fminf(fmaxf(cy / 224.0f * 1023.0f, 0.0f), 1023.0f);
  const int xpos = (int)fminf(fmaxf(cx / 224.0f * 1023.0f, 0.0f), 1023.0f);

  const float4 v = ((const float4*)(x + ((size_t)b * K_ + k) * D_))[t];
  const int e = 4 * t;
  const float* crow;
  int coff;
  if (e < 512) {  // first half uses x_rope (coords[...,1]); wave-uniform branch
    crow = cache + (size_t)xpos * 512;
    coff = e;
  } else {
    crow = cache + (size_t)ypos * 512;
    coff = e - 512;
  }
  const float4 cs = *(const float4*)(crow + coff);  // (c0,s0,c1,s1)
  float4 o;
  o.x = v.x * cs.x - v.y * cs.y;
  o.y = v.x * cs.y + v.y * cs.x;
  o.z = v.z * cs.z - v.w * cs.w;
  o.w = v.z * cs.w + v.w * cs.z;
  ((float4*)(tok + ((size_t)b * K_ + r) * D_))[t] = o;
}

// ---------------------------------------------------------------------------
// Kernel 3: fp32 NT GEMM:  C[m][n] = sum_k A[m][k]*W[n][k] + bias[n]
// 64x64x16 tile, 256 threads, 4x4 micro-tile. Optional row scatter on store.
// ---------------------------------------------------------------------------
__global__ __launch_bounds__(256) void gemm_nt(
    const float* __restrict__ A, long long sAb, const float* __restrict__ W,
    const float* __restrict__ bias, float* __restrict__ C, long long sCb,
    int ldc, int Kd, const int* __restrict__ scat, int sScb) {
  __shared__ __align__(16) float As[16][68];
  __shared__ __align__(16) float Ws[16][68];
  const int tid = threadIdx.x;
  const int tn = tid & 15, tm = tid >> 4;
  const int n0 = blockIdx.x * 64, m0 = blockIdx.y * 64, b = blockIdx.z;
  const int lrow = tid >> 2;         // 0..63
  const int lk4 = (tid & 3) << 2;    // 0,4,8,12

  const float* Ald = A + (long long)b * sAb + (size_t)(m0 + lrow) * Kd + lk4;
  const float* Wld = W + (size_t)(n0 + lrow) * Kd + lk4;
  float acc[4][4] = {{0.f}};

  float4 a4 = *(const float4*)(Ald);
  float4 w4 = *(const float4*)(Wld);
  for (int k0 = 0; k0 < Kd; k0 += 16) {
    As[lk4 + 0][lrow] = a4.x;
    As[lk4 + 1][lrow] = a4.y;
    As[lk4 + 2][lrow] = a4.z;
    As[lk4 + 3][lrow] = a4.w;
    Ws[lk4 + 0][lrow] = w4.x;
    Ws[lk4 + 1][lrow] = w4.y;
    Ws[lk4 + 2][lrow] = w4.z;
    Ws[lk4 + 3][lrow] = w4.w;
    __syncthreads();
    if (k0 + 16 < Kd) {
      a4 = *(const float4*)(Ald + k0 + 16);
      w4 = *(const float4*)(Wld + k0 + 16);
    }
#pragma unroll
    for (int kk = 0; kk < 16; ++kk) {
      const float4 av = *(const float4*)&As[kk][tm << 2];
      const float4 wv = *(const float4*)&Ws[kk][tn << 2];
      acc[0][0] += av.x * wv.x; acc[0][1] += av.x * wv.y;
      acc[0][2] += av.x * wv.z; acc[0][3] += av.x * wv.w;
      acc[1][0] += av.y * wv.x; acc[1][1] += av.y * wv.y;
      acc[1][2] += av.y * wv.z; acc[1][3] += av.y * wv.w;
      acc[2][0] += av.z * wv.x; acc[2][1] += av.z * wv.y;
      acc[2][2] += av.z * wv.z; acc[2][3] += av.z * wv.w;
      acc[3][0] += av.w * wv.x; acc[3][1] += av.w * wv.y;
      acc[3][2] += av.w * wv.z; acc[3][3] += av.w * wv.w;
    }
    __syncthreads();
  }
  const float4 bv = *(const float4*)(bias + n0 + (tn << 2));
#pragma unroll
  for (int i = 0; i < 4; ++i) {
    const int m = m0 + (tm << 2) + i;
    const int orow = scat ? scat[(long long)b * sScb + m] : m;
    float4 o;
    o.x = acc[i][0] + bv.x;
    o.y = acc[i][1] + bv.y;
    o.z = acc[i][2] + bv.z;
    o.w = acc[i][3] + bv.w;
    *(float4*)(C + (long long)b * sCb + (size_t)orow * ldc + n0 + (tn << 2)) = o;
  }
}

// ---------------------------------------------------------------------------
// Kernel 4: flash attention, fp32. Block = 64 queries x one head.
// Q pre-scaled by 1/8. S tile stored transposed St[k][q] for the PV pass.
// ---------------------------------------------------------------------------
__global__ __launch_bounds__(256) void attn_kernel(
    const float* __restrict__ Q, long long sQb, int ldq,
    const float* __restrict__ Kp, long long sKb, int ldk,
    const float* __restrict__ V, long long sVb, int ldv,
    float* __restrict__ O, long long sOb, int ldo) {
  __shared__ __align__(16) float Qs[64][68];
  __shared__ __align__(16) float KVs[64][68];
  __shared__ __align__(16) float St[64][68];  // St[k][q]
  __shared__ float mrow[64], lrow[64], arow[64];
  const int tid = threadIdx.x;
  const int tn = tid & 15, tm = tid >> 4;
  const int q0 = blockIdx.x * 64, h = blockIdx.y, b = blockIdx.z;
  const float* Qb = Q + (long long)b * sQb + h * HD_;
  const float* Kb = Kp + (long long)b * sKb + h * HD_;
  const float* Vb = V + (long long)b * sVb + h * HD_;
  const int lr = tid >> 4, lc4 = (tid & 15) << 2;

#pragma unroll
  for (int it = 0; it < 4; ++it) {
    float4 v = *(const float4*)(Qb + (size_t)(q0 + lr + it * 16) * ldq + lc4);
    v.x *= 0.125f; v.y *= 0.125f; v.z *= 0.125f; v.w *= 0.125f;
    *(float4*)&Qs[lr + it * 16][lc4] = v;
  }
  if (tid < 64) {
    mrow[tid] = -1e30f;
    lrow[tid] = 0.f;
  }
  float accO[4][4] = {{0.f}};

  for (int kt = 0; kt < 16; ++kt) {
    __syncthreads();  // Qs ready / prev PV done
#pragma unroll
    for (int it = 0; it < 4; ++it)
      *(float4*)&KVs[lr + it * 16][lc4] =
          *(const float4*)(Kb + (size_t)(kt * 64 + lr + it * 16) * ldk + lc4);
    __syncthreads();
    // S = Q K^T (scaled): s[i][j], q = tm*4+i, k = tn*4+j
    float s[4][4] = {{0.f}};
#pragma unroll
    for (int d4 = 0; d4 < 16; ++d4) {
      float4 qa[4], kb4[4];
#pragma unroll
      for (int i = 0; i < 4; ++i) qa[i] = *(const float4*)&Qs[(tm << 2) + i][d4 << 2];
#pragma unroll
      for (int j = 0; j < 4; ++j) kb4[j] = *(const float4*)&KVs[(tn << 2) + j][d4 << 2];
#pragma unroll
      for (int i = 0; i < 4; ++i)
#pragma unroll
        for (int j = 0; j < 4; ++j)
          s[i][j] += qa[i].x * kb4[j].x + qa[i].y * kb4[j].y +
                     qa[i].z * kb4[j].z + qa[i].w * kb4[j].w;
    }
#pragma unroll
    for (int i = 0; i < 4; ++i)
#pragma unroll
      for (int j = 0; j < 4; ++j) St[(tn << 2) + j][(tm << 2) + i] = s[i][j];
    __syncthreads();
    // V load (into KVs) + online softmax on St (threads 0..63)
#pragma unroll
    for (int it = 0; it < 4; ++it)
      *(float4*)&KVs[lr + it * 16][lc4] =
          *(const float4*)(Vb + (size_t)(kt * 64 + lr + it * 16) * ldv + lc4);
    if (tid < 64) {
      const float mold = mrow[tid];
      float mx = mold;
#pragma unroll
      for (int k = 0; k < 64; ++k) mx = fmaxf(mx, St[k][tid]);
      const float alpha = __expf(mold - mx);
      float sum = 0.f;
#pragma unroll
      for (int k = 0; k < 64; ++k) {
        const float p = __expf(St[k][tid] - mx);
        St[k][tid] = p;
        sum += p;
      }
      lrow[tid] = lrow[tid] * alpha + sum;
      mrow[tid] = mx;
      arow[tid] = alpha;
    }
    __syncthreads();
    float al[4];
#pragma unroll
    for (int i = 0; i < 4; ++i) al[i] = arow[(tm << 2) + i];
#pragma unroll
    for (int i = 0; i < 4; ++i)
#pragma unroll
      for (int j = 0; j < 4; ++j) accO[i][j] *= al[i];
#pragma unroll
    for (int kk = 0; kk < 64; ++kk) {
      const float4 pv = *(const float4*)&St[kk][tm << 2];
      const float4 vv = *(const float4*)&KVs[kk][tn << 2];
      accO[0][0] += pv.x * vv.x; accO[0][1] += pv.x * vv.y;
      accO[0][2] += pv.x * vv.z; accO[0][3] += pv.x * vv.w;
      accO[1][0] += pv.y * vv.x; accO[1][1] += pv.y * vv.y;
      accO[1][2] += pv.y * vv.z; accO[1][3] += pv.y * vv.w;
      accO[2][0] += pv.z * vv.x; accO[2][1] += pv.z * vv.y;
      accO[2][2] += pv.z * vv.z; accO[2][3] += pv.z * vv.w;
      accO[3][0] += pv.w * vv.x; accO[3][1] += pv.w * vv.y;
      accO[3][2] += pv.w * vv.z; accO[3][3] += pv.w * vv.w;
    }
  }
#pragma unroll
  for (int i = 0; i < 4; ++i) {
    const float inv = 1.0f / lrow[(tm << 2) + i];
    float4 ov;
    ov.x = accO[i][0] * inv;
    ov.y = accO[i][1] * inv;
    ov.z = accO[i][2] * inv;
    ov.w = accO[i][3] * inv;
    *(float4*)(O + (long long)b * sOb + (size_t)(q0 + (tm << 2) + i) * ldo +
               h * HD_ + (tn << 2)) = ov;
  }
}

// ---------------------------------------------------------------------------
extern "C" void kernel_launch(void* const* d_in, const int* in_sizes, int n_in,
                              void* d_out, int out_size, void* d_ws,
                              size_t ws_size, hipStream_t stream) {
  const float* x = (const float*)d_in[0];
  const float* coords = (const float*)d_in[1];
  const unsigned char* isctx = (const unsigned char*)d_in[2];
  const float* rope = (const float*)d_in[3];
  const float* ctx_in_w = (const float*)d_in[4];
  const float* ctx_in_b = (const float*)d_in[5];
  const float* ctx_out_w = (const float*)d_in[6];
  const float* ctx_out_b = (const float*)d_in[7];
  const float* tgt_in_w = (const float*)d_in[8];
  const float* tgt_in_b = (const float*)d_in[9];
  const float* tgt_out_w = (const float*)d_in[10];
  const float* tgt_out_b = (const float*)d_in[11];
  float* out = (float*)d_out;

  // ws layout (floats): tok 8388608 | QKVc 12582912 | KVt 8388608 | Qt 4194304
  // then pos/ipos ints. Total ~128.1 MB.
  float* ws = (float*)d_ws;
  float* tok = ws;
  float* QKVc = tok + (size_t)B_ * K_ * D_;
  float* KVt = QKVc + (size_t)B_ * NCTX_ * 3 * D_;
  float* Qt = KVt + (size_t)B_ * NCTX_ * 2 * D_;
  int* pos = (int*)(Qt + (size_t)B_ * NCTX_ * D_);
  int* ipos = pos + B_ * K_;

  partition_kernel<<<B_, 256, 0, stream>>>(isctx, pos, ipos);
  rope_kernel<<<B_ * K_, 256, 0, stream>>>(x, coords, rope, ipos, tok);

  // Projections: QKV_ctx (ctx rows x ctx_in_w), KV_tgt (ctx rows x tgt wk/wv),
  // Q_tgt (tgt rows x tgt wq)
  gemm_nt<<<dim3(48, 16, B_), 256, 0, stream>>>(
      tok, (long long)K_ * D_, ctx_in_w, ctx_in_b, QKVc,
      (long long)NCTX_ * 3 * D_, 3 * D_, D_, nullptr, 0);
  gemm_nt<<<dim3(32, 16, B_), 256, 0, stream>>>(
      tok, (long long)K_ * D_, tgt_in_w + (size_t)D_ * D_, tgt_in_b + D_, KVt,
      (long long)NCTX_ * 2 * D_, 2 * D_, D_, nullptr, 0);
  gemm_nt<<<dim3(16, 16, B_), 256, 0, stream>>>(
      tok + (size_t)NCTX_ * D_, (long long)K_ * D_, tgt_in_w, tgt_in_b, Qt,
      (long long)NCTX_ * D_, D_, D_, nullptr, 0);

  // Attention (outputs overwrite tok): ctx self-attn, tgt cross-attn
  attn_kernel<<<dim3(16, H_, B_), 256, 0, stream>>>(
      QKVc, (long long)NCTX_ * 3 * D_, 3 * D_, QKVc + D_,
      (long long)NCTX_ * 3 * D_, 3 * D_, QKVc + 2 * D_,
      (long long)NCTX_ * 3 * D_, 3 * D_, tok, (long long)K_ * D_, D_);
  attn_kernel<<<dim3(16, H_, B_), 256, 0, stream>>>(
      Qt, (long long)NCTX_ * D_, D_, KVt, (long long)NCTX_ * 2 * D_, 2 * D_,
      KVt + D_, (long long)NCTX_ * 2 * D_, 2 * D_, tok + (size_t)NCTX_ * D_,
      (long long)K_ * D_, D_);

  // Output projections, scattered back to original token order via ipos
  gemm_nt<<<dim3(16, 16, B_), 256, 0, stream>>>(
      tok, (long long)K_ * D_, ctx_out_w, ctx_out_b, out, (long long)K_ * D_,
      D_, D_, ipos, K_);
  gemm_nt<<<dim3(16, 16, B_), 256, 0, stream>>>(
      tok + (size_t)NCTX_ * D_, (long long)K_ * D_, tgt_out_w, tgt_out_b, out,
      (long long)K_ * D_, D_, D_, ipos + NCTX_, K_);
}

// Round 2
// 679.238 us; speedup vs baseline: 3.3238x; 3.3238x over previous
//
#include <hip/hip_runtime.h>
#include <math.h>

#define B_    4
#define K_    2048
#define D_    1024
#define H_    16
#define NCTX_ 1024

typedef unsigned short ushort_t;
typedef __attribute__((ext_vector_type(8))) __bf16 bf16x8;
typedef __attribute__((ext_vector_type(4))) float f32x4;

__device__ __forceinline__ ushort_t f2bf(float f) {
  unsigned u = __float_as_uint(f);
  u += 0x7fffu + ((u >> 16) & 1u);
  return (ushort_t)(u >> 16);
}
__device__ __forceinline__ float bf2f(ushort_t h) {
  return __uint_as_float(((unsigned)h) << 16);
}
__device__ __forceinline__ void gload16(const void* g, void* l) {
  __builtin_amdgcn_global_load_lds(
      (const __attribute__((address_space(1))) unsigned int*)g,
      (__attribute__((address_space(3))) unsigned int*)l, 16, 0, 0);
}

// ---------------------------------------------------------------------------
// Kernel 1: partition scan (unchanged from R1 — verified).
// ---------------------------------------------------------------------------
__global__ __launch_bounds__(256) void partition_kernel(
    const unsigned char* __restrict__ isctx, int* __restrict__ pos,
    int* __restrict__ ipos) {
  const int b = blockIdx.x;
  const int tid = threadIdx.x;
  const int wid = tid >> 6, lane = tid & 63;
  __shared__ int csum[4];
  __shared__ int waveTot[4];
  __shared__ int strideSh;

  int cnt = 0;
  for (int i = 0; i < 32; ++i) cnt += (isctx[tid * 32 + i] != 0);
  for (int off = 32; off; off >>= 1) cnt += __shfl_down(cnt, off, 64);
  if (lane == 0) csum[wid] = cnt;
  __syncthreads();
  if (tid == 0) {
    int t = csum[0] + csum[1] + csum[2] + csum[3];
    strideSh = (t > 2048) ? 1 : ((t > 768) ? 4 : 8);
  }
  __syncthreads();
  const int stride = strideSh;

  const unsigned char* base = isctx + (size_t)b * K_ * stride;
  int f[8];
  int s = 0;
  for (int i = 0; i < 8; ++i) {
    f[i] = base[(size_t)(tid * 8 + i) * stride] != 0;
    s += f[i];
  }
  int inc = s;
  for (int off = 1; off < 64; off <<= 1) {
    int v = __shfl_up(inc, off, 64);
    if (lane >= off) inc += v;
  }
  if (lane == 63) waveTot[wid] = inc;
  __syncthreads();
  int wOff = 0;
  for (int w = 0; w < wid; ++w) wOff += waveTot[w];
  int run = wOff + inc - s;
  for (int i = 0; i < 8; ++i) {
    int k = tid * 8 + i;
    int p;
    if (f[i]) {
      p = run;
      run++;
    } else {
      p = NCTX_ + k - run;
    }
    pos[b * K_ + k] = p;
    ipos[b * K_ + p] = k;
  }
}

// ---------------------------------------------------------------------------
// Kernel 2: RoPE + permute-gather -> split-bf16 (hi/lo) token buffer.
// ---------------------------------------------------------------------------
__global__ __launch_bounds__(256) void rope_kernel(
    const float* __restrict__ x, const float* __restrict__ coords,
    const float* __restrict__ cache, const int* __restrict__ ipos,
    ushort_t* __restrict__ tokhi, ushort_t* __restrict__ toklo) {
  const int row = blockIdx.x;
  const int b = row >> 11;
  const int r = row & (K_ - 1);
  const int k = ipos[row];
  const int t = threadIdx.x;

  const float cy = coords[(size_t)(b * K_ + k) * 2 + 0];
  const float cx = coords[(size_t)(b * K_ + k) * 2 + 1];
  const int ypos = (int)fminf(fmaxf(cy / 224.0f * 1023.0f, 0.0f), 1023.0f);
  const int xpos = (int)fminf(fmaxf(cx / 224.0f * 1023.0f, 0.0f), 1023.0f);

  const float4 v = ((const float4*)(x + ((size_t)b * K_ + k) * D_))[t];
  const int e = 4 * t;
  const float* crow;
  int coff;
  if (e < 512) {
    crow = cache + (size_t)xpos * 512;
    coff = e;
  } else {
    crow = cache + (size_t)ypos * 512;
    coff = e - 512;
  }
  const float4 cs = *(const float4*)(crow + coff);
  float4 o;
  o.x = v.x * cs.x - v.y * cs.y;
  o.y = v.x * cs.y + v.y * cs.x;
  o.z = v.z * cs.z - v.w * cs.w;
  o.w = v.z * cs.w + v.w * cs.z;
  ushort4 h, l;
  h.x = f2bf(o.x); l.x = f2bf(o.x - bf2f(h.x));
  h.y = f2bf(o.y); l.y = f2bf(o.y - bf2f(h.y));
  h.z = f2bf(o.z); l.z = f2bf(o.z - bf2f(h.z));
  h.w = f2bf(o.w); l.w = f2bf(o.w - bf2f(h.w));
  ((ushort4*)(tokhi + ((size_t)b * K_ + r) * D_))[t] = h;
  ((ushort4*)(toklo + ((size_t)b * K_ + r) * D_))[t] = l;
}

// ---------------------------------------------------------------------------
// Kernel 3: fp32 -> split-bf16 conversion (weights).
// ---------------------------------------------------------------------------
__global__ __launch_bounds__(256) void cvt_kernel(
    const float* __restrict__ src, ushort_t* __restrict__ hi,
    ushort_t* __restrict__ lo, int n4) {
  const int i = blockIdx.x * 256 + threadIdx.x;
  if (i >= n4) return;
  const float4 v = ((const float4*)src)[i];
  ushort4 h, l;
  h.x = f2bf(v.x); l.x = f2bf(v.x - bf2f(h.x));
  h.y = f2bf(v.y); l.y = f2bf(v.y - bf2f(h.y));
  h.z = f2bf(v.z); l.z = f2bf(v.z - bf2f(h.z));
  h.w = f2bf(v.w); l.w = f2bf(v.w - bf2f(h.w));
  ((ushort4*)hi)[i] = h;
  ((ushort4*)lo)[i] = l;
}

// ---------------------------------------------------------------------------
// Kernel 4: split-bf16 MFMA GEMM.  C[m][n] = sum_k A[m][k] W[n][k] + bias[n]
// 128x128x32 tile, 4 waves (2x2 of 64x64), 16x16x32 bf16 MFMA, split3.
// LDS layout per tile: chunk(c = koctet*128 + row) of 16B at offset c*16.
// Output: fp32 with row scatter (Cf) or bf16-hi (Ch).
// ---------------------------------------------------------------------------
__global__ __launch_bounds__(256) void gemm_mfma(
    const ushort_t* __restrict__ Ahi, const ushort_t* __restrict__ Alo,
    long long sAb, const ushort_t* __restrict__ Whi,
    const ushort_t* __restrict__ Wlo, const float* __restrict__ bias,
    float* __restrict__ Cf, ushort_t* __restrict__ Ch, long long sCb, int ldc,
    int Kd, const int* __restrict__ scat, int sScb) {
  __shared__ ushort_t lds[16384];  // Ahi | Alo | Whi | Wlo (8 KB each)
  const int tid = threadIdx.x;
  const int wave = tid >> 6, lane = tid & 63;
  const int quad = lane >> 4, m16 = lane & 15;
  const int n0 = blockIdx.x * 128, m0 = blockIdx.y * 128, b = blockIdx.z;
  const int wm = (wave & 1) << 6, wn = (wave >> 1) << 6;

  const ushort_t* As[2] = {Ahi + (long long)b * sAb, Alo + (long long)b * sAb};
  const ushort_t* Wsrc[2] = {Whi, Wlo};

  f32x4 acc[4][4];
  const f32x4 z = {0.f, 0.f, 0.f, 0.f};
#pragma unroll
  for (int i = 0; i < 4; ++i)
#pragma unroll
    for (int j = 0; j < 4; ++j) acc[i][j] = z;

  for (int k0 = 0; k0 < Kd; k0 += 32) {
#pragma unroll
    for (int j = 0; j < 8; ++j) {
      const int t = j >> 1;
      const int c = ((j & 1) * 4 + wave) * 64 + lane;
      const int q = c >> 7, r = c & 127;
      const ushort_t* g =
          (t < 2) ? (As[t] + (size_t)(m0 + r) * Kd + k0 + q * 8)
                  : (Wsrc[t - 2] + (size_t)(n0 + r) * Kd + k0 + q * 8);
      gload16(g, &lds[t * 4096 + c * 8]);
    }
    __syncthreads();
    bf16x8 af[2][4], wf[2][4];
#pragma unroll
    for (int i = 0; i < 4; ++i) {
      const int ar = (quad * 128 + wm + i * 16 + m16) * 8;
      af[0][i] = *(const bf16x8*)&lds[ar];
      af[1][i] = *(const bf16x8*)&lds[4096 + ar];
      const int wr = (quad * 128 + wn + i * 16 + m16) * 8;
      wf[0][i] = *(const bf16x8*)&lds[8192 + wr];
      wf[1][i] = *(const bf16x8*)&lds[12288 + wr];
    }
#pragma unroll
    for (int i = 0; i < 4; ++i)
#pragma unroll
      for (int j = 0; j < 4; ++j) {
        acc[i][j] = __builtin_amdgcn_mfma_f32_16x16x32_bf16(af[0][i], wf[0][j],
                                                            acc[i][j], 0, 0, 0);
        acc[i][j] = __builtin_amdgcn_mfma_f32_16x16x32_bf16(af[0][i], wf[1][j],
                                                            acc[i][j], 0, 0, 0);
        acc[i][j] = __builtin_amdgcn_mfma_f32_16x16x32_bf16(af[1][i], wf[0][j],
                                                            acc[i][j], 0, 0, 0);
      }
    __syncthreads();
  }
#pragma unroll
  for (int j = 0; j < 4; ++j) {
    const int col = n0 + wn + j * 16 + m16;
    const float bv = bias[col];
#pragma unroll
    for (int i = 0; i < 4; ++i) {
      const int mr = m0 + wm + i * 16 + quad * 4;
#pragma unroll
      for (int r = 0; r < 4; ++r) {
        const float v = acc[i][j][r] + bv;
        const int row = mr + r;
        if (Cf) {
          const int orow = scat[(long long)b * sScb + row];
          Cf[(long long)b * sCb + (size_t)orow * ldc + col] = v;
        } else {
          Ch[(long long)b * sCb + (size_t)row * ldc + col] = f2bf(v);
        }
      }
    }
  }
}

// ---------------------------------------------------------------------------
// Kernel 5: V transpose -> Vt[(b*H+h)*64 + d][1024 tokens] (bf16).
// ---------------------------------------------------------------------------
__global__ __launch_bounds__(256) void vtrans_kernel(
    const ushort_t* __restrict__ V, long long sVb, int ldv, int coloff,
    ushort_t* __restrict__ Vt) {
  __shared__ __align__(16) ushort_t tile[64][72];
  const int tblk = blockIdx.x, h = blockIdx.y, b = blockIdx.z;
  const int tid = threadIdx.x;
  const ushort_t* src =
      V + (long long)b * sVb + (size_t)(tblk * 64) * ldv + coloff + h * 64;
#pragma unroll
  for (int j = 0; j < 2; ++j) {
    const int c = j * 256 + tid;
    const int r = c >> 3, dc = c & 7;
    *(uint4*)&tile[r][dc * 8] = *(const uint4*)(src + (size_t)r * ldv + dc * 8);
  }
  __syncthreads();
  ushort_t* dst = Vt + (size_t)(b * H_ + h) * 64 * 1024 + tblk * 64;
#pragma unroll
  for (int j = 0; j < 2; ++j) {
    const int c = j * 256 + tid;
    const int d = c >> 3, tc = c & 7;
    union {
      ushort_t u[8];
      uint4 v;
    } t;
#pragma unroll
    for (int i = 0; i < 8; ++i) t.u[i] = tile[tc * 8 + i][d];
    *(uint4*)(dst + (size_t)d * 1024 + tc * 8) = t.v;
  }
}

// ---------------------------------------------------------------------------
// Kernel 6: MFMA flash attention. Block = 64 queries x one head, 4 waves;
// wave w owns q-rows [q0+16w, +16). QK and PV in plain bf16 MFMA, fp32
// online softmax via quad-group shfl_xor (no LDS for stats). P round-trips
// through wave-private LDS to enter PV in A-layout. Output split-bf16.
// ---------------------------------------------------------------------------
__global__ __launch_bounds__(256) void attn_mfma(
    const ushort_t* __restrict__ Qp, long long sQb, int ldq,
    const ushort_t* __restrict__ Kp, long long sKb, int ldk,
    const ushort_t* __restrict__ Vt, ushort_t* __restrict__ Ohi,
    ushort_t* __restrict__ Olo, long long sOb) {
  __shared__ ushort_t Qs[4096];  // chunk c = doctet*64 + qrow
  __shared__ ushort_t Ks[4096];  // chunk c = doctet*64 + keyrow
  __shared__ ushort_t Vs[4096];  // chunk c = koctet*64 + d
  __shared__ ushort_t Ps[4096];  // per-wave 1024: chunk = koctet*16 + qrow
  const int tid = threadIdx.x, wave = tid >> 6, lane = tid & 63;
  const int quad = lane >> 4, m16 = lane & 15;
  const int q0 = blockIdx.x * 64, h = blockIdx.y, b = blockIdx.z;
  const ushort_t* Qb = Qp + (long long)b * sQb + h * 64;
  const ushort_t* Kb = Kp + (long long)b * sKb + h * 64;
  const ushort_t* Vb = Vt + (size_t)(b * H_ + h) * 64 * 1024;

#pragma unroll
  for (int j = 0; j < 2; ++j) {
    const int c = j * 256 + wave * 64 + lane;
    gload16(Qb + (size_t)(q0 + (c & 63)) * ldq + (c >> 6) * 8, &Qs[c * 8]);
  }
  float m_run[4], l_run[4];
#pragma unroll
  for (int r = 0; r < 4; ++r) {
    m_run[r] = -1e30f;
    l_run[r] = 0.f;
  }
  f32x4 Oa[4];
  const f32x4 z = {0.f, 0.f, 0.f, 0.f};
#pragma unroll
  for (int j = 0; j < 4; ++j) Oa[j] = z;

  for (int kt = 0; kt < 16; ++kt) {
#pragma unroll
    for (int j = 0; j < 2; ++j) {
      const int c = j * 256 + wave * 64 + lane;
      gload16(Kb + (size_t)(kt * 64 + (c & 63)) * ldk + (c >> 6) * 8,
              &Ks[c * 8]);
      gload16(Vb + (size_t)(c & 63) * 1024 + kt * 64 + (c >> 6) * 8,
              &Vs[c * 8]);
    }
    __syncthreads();
    const bf16x8 qf0 = *(const bf16x8*)&Qs[(quad * 64 + wave * 16 + m16) * 8];
    const bf16x8 qf1 =
        *(const bf16x8*)&Qs[((4 + quad) * 64 + wave * 16 + m16) * 8];
    f32x4 S[4];
#pragma unroll
    for (int jn = 0; jn < 4; ++jn) {
      S[jn] = z;
      const bf16x8 kf0 = *(const bf16x8*)&Ks[(quad * 64 + jn * 16 + m16) * 8];
      const bf16x8 kf1 =
          *(const bf16x8*)&Ks[((4 + quad) * 64 + jn * 16 + m16) * 8];
      S[jn] = __builtin_amdgcn_mfma_f32_16x16x32_bf16(qf0, kf0, S[jn], 0, 0, 0);
      S[jn] = __builtin_amdgcn_mfma_f32_16x16x32_bf16(qf1, kf1, S[jn], 0, 0, 0);
    }
#pragma unroll
    for (int jn = 0; jn < 4; ++jn) S[jn] *= 0.125f;
    float mnew[4], al[4], rs[4];
#pragma unroll
    for (int r = 0; r < 4; ++r) {
      float mx = fmaxf(fmaxf(S[0][r], S[1][r]), fmaxf(S[2][r], S[3][r]));
      mx = fmaxf(mx, __shfl_xor(mx, 1, 64));
      mx = fmaxf(mx, __shfl_xor(mx, 2, 64));
      mx = fmaxf(mx, __shfl_xor(mx, 4, 64));
      mx = fmaxf(mx, __shfl_xor(mx, 8, 64));
      mnew[r] = fmaxf(m_run[r], mx);
      al[r] = __expf(m_run[r] - mnew[r]);
      m_run[r] = mnew[r];
      rs[r] = 0.f;
    }
#pragma unroll
    for (int jn = 0; jn < 4; ++jn)
#pragma unroll
      for (int r = 0; r < 4; ++r) {
        const float p = __expf(S[jn][r] - mnew[r]);
        S[jn][r] = p;
        rs[r] += p;
      }
#pragma unroll
    for (int r = 0; r < 4; ++r) {
      float s = rs[r];
      s += __shfl_xor(s, 1, 64);
      s += __shfl_xor(s, 2, 64);
      s += __shfl_xor(s, 4, 64);
      s += __shfl_xor(s, 8, 64);
      l_run[r] = l_run[r] * al[r] + s;
    }
#pragma unroll
    for (int j = 0; j < 4; ++j) {
      Oa[j][0] *= al[0];
      Oa[j][1] *= al[1];
      Oa[j][2] *= al[2];
      Oa[j][3] *= al[3];
    }
    ushort_t* Pw = Ps + wave * 1024;
#pragma unroll
    for (int jn = 0; jn < 4; ++jn)
#pragma unroll
      for (int r = 0; r < 4; ++r)
        Pw[((jn * 2 + (m16 >> 3)) * 16 + quad * 4 + r) * 8 + (m16 & 7)] =
            f2bf(S[jn][r]);
    const bf16x8 pf0 = *(const bf16x8*)&Pw[(quad * 16 + m16) * 8];
    const bf16x8 pf1 = *(const bf16x8*)&Pw[((4 + quad) * 16 + m16) * 8];
#pragma unroll
    for (int jd = 0; jd < 4; ++jd) {
      const bf16x8 vf0 = *(const bf16x8*)&Vs[(quad * 64 + jd * 16 + m16) * 8];
      const bf16x8 vf1 =
          *(const bf16x8*)&Vs[((4 + quad) * 64 + jd * 16 + m16) * 8];
      Oa[jd] = __builtin_amdgcn_mfma_f32_16x16x32_bf16(pf0, vf0, Oa[jd], 0, 0, 0);
      Oa[jd] = __builtin_amdgcn_mfma_f32_16x16x32_bf16(pf1, vf1, Oa[jd], 0, 0, 0);
    }
    __syncthreads();
  }
#pragma unroll
  for (int jd = 0; jd < 4; ++jd)
#pragma unroll
    for (int r = 0; r < 4; ++r) {
      const float v = Oa[jd][r] / l_run[r];
      const ushort_t hi = f2bf(v);
      const ushort_t lo = f2bf(v - bf2f(hi));
      const size_t off = (long long)b * sOb +
                         (size_t)(q0 + wave * 16 + quad * 4 + r) * D_ + h * 64 +
                         jd * 16 + m16;
      Ohi[off] = hi;
      Olo[off] = lo;
    }
}

// ---------------------------------------------------------------------------
extern "C" void kernel_launch(void* const* d_in, const int* in_sizes, int n_in,
                              void* d_out, int out_size, void* d_ws,
                              size_t ws_size, hipStream_t stream) {
  const float* x = (const float*)d_in[0];
  const float* coords = (const float*)d_in[1];
  const unsigned char* isctx = (const unsigned char*)d_in[2];
  const float* rope = (const float*)d_in[3];
  const float* ctx_in_w = (const float*)d_in[4];
  const float* ctx_in_b = (const float*)d_in[5];
  const float* ctx_out_w = (const float*)d_in[6];
  const float* ctx_out_b = (const float*)d_in[7];
  const float* tgt_in_w = (const float*)d_in[8];
  const float* tgt_in_b = (const float*)d_in[9];
  const float* tgt_out_w = (const float*)d_in[10];
  const float* tgt_out_b = (const float*)d_in[11];
  float* out = (float*)d_out;

  // ws layout (ushort units): tokhi 8M | toklo 8M | whi 8M | wlo 8M |
  // qkvc 12M | kvt 8M | qt 4M | vt 4M | pos/ipos ints  (~126 MB)
  ushort_t* ws = (ushort_t*)d_ws;
  ushort_t* tokhi = ws;
  ushort_t* toklo = tokhi + 8388608;
  ushort_t* whi = toklo + 8388608;
  ushort_t* wlo = whi + 8388608;
  ushort_t* qkvc = wlo + 8388608;
  ushort_t* kvt = qkvc + 12582912;
  ushort_t* qt = kvt + 8388608;
  ushort_t* vt = qt + 4194304;
  int* pos = (int*)(vt + 4194304);
  int* ipos = pos + B_ * K_;

  // weight sub-offsets in whi/wlo: ctx_in 0 | ctx_out 3145728 |
  // tgt_in 4194304 | tgt_out 7340032
  partition_kernel<<<B_, 256, 0, stream>>>(isctx, pos, ipos);
  cvt_kernel<<<3072, 256, 0, stream>>>(ctx_in_w, whi, wlo, 786432);
  cvt_kernel<<<1024, 256, 0, stream>>>(ctx_out_w, whi + 3145728,
                                       wlo + 3145728, 262144);
  cvt_kernel<<<3072, 256, 0, stream>>>(tgt_in_w, whi + 4194304, wlo + 4194304,
                                       786432);
  cvt_kernel<<<1024, 256, 0, stream>>>(tgt_out_w, whi + 7340032,
                                       wlo + 7340032, 262144);
  rope_kernel<<<B_ * K_, 256, 0, stream>>>(x, coords, rope, ipos, tokhi, toklo);

  // Projections (split3 MFMA, bf16-hi outputs)
  gemm_mfma<<<dim3(24, 8, B_), 256, 0, stream>>>(
      tokhi, toklo, (long long)K_ * D_, whi, wlo, ctx_in_b, nullptr, qkvc,
      (long long)NCTX_ * 3 * D_, 3 * D_, D_, nullptr, 0);
  gemm_mfma<<<dim3(16, 8, B_), 256, 0, stream>>>(
      tokhi, toklo, (long long)K_ * D_, whi + 4194304 + D_ * D_,
      wlo + 4194304 + D_ * D_, tgt_in_b + D_, nullptr, kvt,
      (long long)NCTX_ * 2 * D_, 2 * D_, D_, nullptr, 0);
  gemm_mfma<<<dim3(8, 8, B_), 256, 0, stream>>>(
      tokhi + (size_t)NCTX_ * D_, toklo + (size_t)NCTX_ * D_,
      (long long)K_ * D_, whi + 4194304, wlo + 4194304, tgt_in_b, nullptr, qt,
      (long long)NCTX_ * D_, D_, D_, nullptr, 0);

  // ctx self-attention (output overwrites tokhi/toklo rows 0..1023)
  vtrans_kernel<<<dim3(16, H_, B_), 256, 0, stream>>>(
      qkvc, (long long)NCTX_ * 3 * D_, 3 * D_, 2 * D_, vt);
  attn_mfma<<<dim3(16, H_, B_), 256, 0, stream>>>(
      qkvc, (long long)NCTX_ * 3 * D_, 3 * D_, qkvc + D_,
      (long long)NCTX_ * 3 * D_, 3 * D_, vt, tokhi, toklo, (long long)K_ * D_);
  // tgt cross-attention (vt buffer reused; stream order serializes)
  vtrans_kernel<<<dim3(16, H_, B_), 256, 0, stream>>>(
      kvt, (long long)NCTX_ * 2 * D_, 2 * D_, D_, vt);
  attn_mfma<<<dim3(16, H_, B_), 256, 0, stream>>>(
      qt, (long long)NCTX_ * D_, D_, kvt, (long long)NCTX_ * 2 * D_, 2 * D_,
      vt, tokhi + (size_t)NCTX_ * D_, toklo + (size_t)NCTX_ * D_,
      (long long)K_ * D_);

  // Output projections (split3 MFMA, fp32 out, scatter to original order)
  gemm_mfma<<<dim3(8, 8, B_), 256, 0, stream>>>(
      tokhi, toklo, (long long)K_ * D_, whi + 3145728, wlo + 3145728,
      ctx_out_b, out, nullptr, (long long)K_ * D_, D_, D_, ipos, K_);
  gemm_mfma<<<dim3(8, 8, B_), 256, 0, stream>>>(
      tokhi + (size_t)NCTX_ * D_, toklo + (size_t)NCTX_ * D_,
      (long long)K_ * D_, whi + 7340032, wlo + 7340032, tgt_out_b, out,
      nullptr, (long long)K_ * D_, D_, D_, ipos + NCTX_, K_);
}

// Round 3
// 525.722 us; speedup vs baseline: 4.2944x; 1.2920x over previous
//
#include <hip/hip_runtime.h>
#include <math.h>

#define B_    4
#define K_    2048
#define D_    1024
#define H_    16
#define NCTX_ 1024

typedef unsigned short ushort_t;
typedef _Float16 f16;
typedef __attribute__((ext_vector_type(8))) _Float16 f16x8;
typedef __attribute__((ext_vector_type(4))) float f32x4;

union U4 {
  f16 h[4];
  ushort4 u;
};

__device__ __forceinline__ void gload16(const void* g, void* l) {
  __builtin_amdgcn_global_load_lds(
      (const __attribute__((address_space(1))) unsigned int*)g,
      (__attribute__((address_space(3))) unsigned int*)l, 16, 0, 0);
}

// ---------------------------------------------------------------------------
// Kernel 1: partition scan (verified R1/R2).
// ---------------------------------------------------------------------------
__global__ __launch_bounds__(256) void partition_kernel(
    const unsigned char* __restrict__ isctx, int* __restrict__ pos,
    int* __restrict__ ipos) {
  const int b = blockIdx.x;
  const int tid = threadIdx.x;
  const int wid = tid >> 6, lane = tid & 63;
  __shared__ int csum[4];
  __shared__ int waveTot[4];
  __shared__ int strideSh;

  int cnt = 0;
  for (int i = 0; i < 32; ++i) cnt += (isctx[tid * 32 + i] != 0);
  for (int off = 32; off; off >>= 1) cnt += __shfl_down(cnt, off, 64);
  if (lane == 0) csum[wid] = cnt;
  __syncthreads();
  if (tid == 0) {
    int t = csum[0] + csum[1] + csum[2] + csum[3];
    strideSh = (t > 2048) ? 1 : ((t > 768) ? 4 : 8);
  }
  __syncthreads();
  const int stride = strideSh;

  const unsigned char* base = isctx + (size_t)b * K_ * stride;
  int f[8];
  int s = 0;
  for (int i = 0; i < 8; ++i) {
    f[i] = base[(size_t)(tid * 8 + i) * stride] != 0;
    s += f[i];
  }
  int inc = s;
  for (int off = 1; off < 64; off <<= 1) {
    int v = __shfl_up(inc, off, 64);
    if (lane >= off) inc += v;
  }
  if (lane == 63) waveTot[wid] = inc;
  __syncthreads();
  int wOff = 0;
  for (int w = 0; w < wid; ++w) wOff += waveTot[w];
  int run = wOff + inc - s;
  for (int i = 0; i < 8; ++i) {
    int k = tid * 8 + i;
    int p;
    if (f[i]) {
      p = run;
      run++;
    } else {
      p = NCTX_ + k - run;
    }
    pos[b * K_ + k] = p;
    ipos[b * K_ + p] = k;
  }
}

// ---------------------------------------------------------------------------
// Kernel 2: RoPE + permute-gather -> split2-f16 (hi/lo) token buffer.
// ---------------------------------------------------------------------------
__global__ __launch_bounds__(256) void rope_kernel(
    const float* __restrict__ x, const float* __restrict__ coords,
    const float* __restrict__ cache, const int* __restrict__ ipos,
    f16* __restrict__ tokhi, f16* __restrict__ toklo) {
  const int row = blockIdx.x;
  const int b = row >> 11;
  const int r = row & (K_ - 1);
  const int k = ipos[row];
  const int t = threadIdx.x;

  const float cy = coords[(size_t)(b * K_ + k) * 2 + 0];
  const float cx = coords[(size_t)(b * K_ + k) * 2 + 1];
  const int ypos = (int)fminf(fmaxf(cy / 224.0f * 1023.0f, 0.0f), 1023.0f);
  const int xpos = (int)fminf(fmaxf(cx / 224.0f * 1023.0f, 0.0f), 1023.0f);

  const float4 v = ((const float4*)(x + ((size_t)b * K_ + k) * D_))[t];
  const int e = 4 * t;
  const float* crow;
  int coff;
  if (e < 512) {
    crow = cache + (size_t)xpos * 512;
    coff = e;
  } else {
    crow = cache + (size_t)ypos * 512;
    coff = e - 512;
  }
  const float4 cs = *(const float4*)(crow + coff);
  float o[4];
  o[0] = v.x * cs.x - v.y * cs.y;
  o[1] = v.x * cs.y + v.y * cs.x;
  o[2] = v.z * cs.z - v.w * cs.w;
  o[3] = v.z * cs.w + v.w * cs.z;
  U4 h, l;
#pragma unroll
  for (int i = 0; i < 4; ++i) {
    h.h[i] = (f16)o[i];
    l.h[i] = (f16)(o[i] - (float)h.h[i]);
  }
  ((ushort4*)(tokhi + ((size_t)b * K_ + r) * D_))[t] = h.u;
  ((ushort4*)(toklo + ((size_t)b * K_ + r) * D_))[t] = l.u;
}

// ---------------------------------------------------------------------------
// Kernel 3: all weights fp32 -> single f16, concatenated:
// [0,3M) ctx_in | [3M,5M) tgt_in kv | [5M,6M) tgt_in q | [6M,7M) ctx_out |
// [7M,8M) tgt_out   (M = 1048576 floats)
// ---------------------------------------------------------------------------
__global__ __launch_bounds__(256) void cvt_all(
    const float* __restrict__ ctx_in_w, const float* __restrict__ tgt_in_w,
    const float* __restrict__ ctx_out_w, const float* __restrict__ tgt_out_w,
    f16* __restrict__ dst) {
  const int i4 = blockIdx.x * 256 + threadIdx.x;  // 0..2097151
  const int f = i4 * 4;
  const float* src;
  if (f < 3145728) src = ctx_in_w + f;
  else if (f < 5242880) src = tgt_in_w + (f - 3145728 + 1048576);
  else if (f < 6291456) src = tgt_in_w + (f - 5242880);
  else if (f < 7340032) src = ctx_out_w + (f - 6291456);
  else src = tgt_out_w + (f - 7340032);
  const float4 v = *(const float4*)src;
  U4 u;
  u.h[0] = (f16)v.x;
  u.h[1] = (f16)v.y;
  u.h[2] = (f16)v.z;
  u.h[3] = (f16)v.w;
  ((ushort4*)dst)[i4] = u.u;
}

// ---------------------------------------------------------------------------
// GEMM core: C[m][n] = sum_k (Ahi+Alo)[m][k] * W[n][k], f16 MFMA, fp32 acc.
// 128x128x32 tile, 4 waves, 2 MFMAs per 16x16 sub-tile per K-step.
// ---------------------------------------------------------------------------
#define GEMM_CORE(AhiP, AloP, WP, Kd)                                         \
  f32x4 acc[4][4];                                                            \
  {                                                                           \
    const f32x4 z = {0.f, 0.f, 0.f, 0.f};                                     \
    for (int i = 0; i < 4; ++i)                                               \
      for (int j = 0; j < 4; ++j) acc[i][j] = z;                              \
  }                                                                           \
  for (int k0 = 0; k0 < Kd; k0 += 32) {                                       \
    _Pragma("unroll") for (int j = 0; j < 6; ++j) {                           \
      const int t = j >> 1;                                                   \
      const int c = ((j & 1) * 4 + wave) * 64 + lane;                         \
      const int q = c >> 7, r = c & 127;                                      \
      const f16* g = (t == 0) ? (AhiP + (size_t)(m0 + r) * Kd + k0 + q * 8)   \
                   : (t == 1) ? (AloP + (size_t)(m0 + r) * Kd + k0 + q * 8)   \
                              : (WP + (size_t)(n0 + r) * Kd + k0 + q * 8);    \
      gload16(g, &lds[t * 4096 + c * 8]);                                     \
    }                                                                         \
    __syncthreads();                                                          \
    f16x8 af[2][4], wf[4];                                                    \
    _Pragma("unroll") for (int i = 0; i < 4; ++i) {                           \
      const int ar = (quad * 128 + wm + i * 16 + m16) * 8;                    \
      af[0][i] = *(const f16x8*)&lds[ar];                                     \
      af[1][i] = *(const f16x8*)&lds[4096 + ar];                              \
      wf[i] = *(const f16x8*)&lds[8192 + (quad * 128 + wn + i * 16 + m16) * 8];\
    }                                                                         \
    _Pragma("unroll") for (int i = 0; i < 4; ++i)                             \
        _Pragma("unroll") for (int j = 0; j < 4; ++j) {                       \
      acc[i][j] =                                                             \
          __builtin_amdgcn_mfma_f32_16x16x32_f16(af[0][i], wf[j], acc[i][j],  \
                                                 0, 0, 0);                    \
      acc[i][j] =                                                             \
          __builtin_amdgcn_mfma_f32_16x16x32_f16(af[1][i], wf[j], acc[i][j],  \
                                                 0, 0, 0);                    \
    }                                                                         \
    __syncthreads();                                                          \
  }

// ---------------------------------------------------------------------------
// Kernel 4: projection GEMM, f16 output split across two destinations at
// column colSplit (D0: ldc0, D1: ldc1). bias1 indexed by (col - colSplit).
// ---------------------------------------------------------------------------
__global__ __launch_bounds__(256) void gemm_proj(
    const f16* __restrict__ Ahi, const f16* __restrict__ Alo, long long sAb,
    const f16* __restrict__ W, const float* __restrict__ bias0,
    const float* __restrict__ bias1, int colSplit, f16* __restrict__ D0,
    long long sD0b, int ldc0, f16* __restrict__ D1, long long sD1b, int ldc1,
    int Kd) {
  __shared__ f16 lds[12288];
  const int tid = threadIdx.x;
  const int wave = tid >> 6, lane = tid & 63;
  const int quad = lane >> 4, m16 = lane & 15;
  const int n0 = blockIdx.x * 128, m0 = blockIdx.y * 128, b = blockIdx.z;
  const int wm = (wave & 1) << 6, wn = (wave >> 1) << 6;
  const f16* AhiB = Ahi + (long long)b * sAb;
  const f16* AloB = Alo + (long long)b * sAb;

  GEMM_CORE(AhiB, AloB, W, Kd)

#pragma unroll
  for (int j = 0; j < 4; ++j) {
    const int col = n0 + wn + j * 16 + m16;
    const float bv = (col < colSplit) ? bias0[col] : bias1[col - colSplit];
#pragma unroll
    for (int i = 0; i < 4; ++i) {
      const int mr = m0 + wm + i * 16 + quad * 4;
#pragma unroll
      for (int r = 0; r < 4; ++r) {
        const float v = acc[i][j][r] + bv;
        if (col < colSplit)
          D0[(long long)b * sD0b + (size_t)(mr + r) * ldc0 + col] = (f16)v;
        else
          D1[(long long)b * sD1b + (size_t)(mr + r) * ldc1 + col - colSplit] =
              (f16)v;
      }
    }
  }
}

// ---------------------------------------------------------------------------
// Kernel 5: merged output projections. z = sel*4 + ... (b = z&3, sel = z>>2).
// fp32 output scattered to original token order.
// ---------------------------------------------------------------------------
__global__ __launch_bounds__(256) void gemm_out(
    const f16* __restrict__ Ahi, const f16* __restrict__ Alo,
    const f16* __restrict__ Wbase, const float* __restrict__ bias_ctx,
    const float* __restrict__ bias_tgt, const int* __restrict__ ipos,
    float* __restrict__ out) {
  __shared__ f16 lds[12288];
  const int tid = threadIdx.x;
  const int wave = tid >> 6, lane = tid & 63;
  const int quad = lane >> 4, m16 = lane & 15;
  const int n0 = blockIdx.x * 128, m0 = blockIdx.y * 128;
  const int b = blockIdx.z & 3, sel = blockIdx.z >> 2;
  const int wm = (wave & 1) << 6, wn = (wave >> 1) << 6;
  const f16* AhiB = Ahi + (size_t)b * K_ * D_ + (size_t)sel * NCTX_ * D_;
  const f16* AloB = Alo + (size_t)b * K_ * D_ + (size_t)sel * NCTX_ * D_;
  const f16* W = Wbase + (size_t)sel * 1048576;
  const float* bias = sel ? bias_tgt : bias_ctx;

  GEMM_CORE(AhiB, AloB, W, D_)

#pragma unroll
  for (int j = 0; j < 4; ++j) {
    const int col = n0 + wn + j * 16 + m16;
    const float bv = bias[col];
#pragma unroll
    for (int i = 0; i < 4; ++i) {
      const int mr = m0 + wm + i * 16 + quad * 4;
#pragma unroll
      for (int r = 0; r < 4; ++r) {
        const int orow = ipos[b * K_ + sel * NCTX_ + mr + r];
        out[(size_t)b * K_ * D_ + (size_t)orow * D_ + col] =
            acc[i][j][r] + bv;
      }
    }
  }
}

// ---------------------------------------------------------------------------
// Kernel 6: V transpose (bit-width agnostic 16-bit moves).
// ---------------------------------------------------------------------------
__global__ __launch_bounds__(256) void vtrans_kernel(
    const ushort_t* __restrict__ V, long long sVb, int ldv, int coloff,
    ushort_t* __restrict__ Vt) {
  __shared__ __align__(16) ushort_t tile[64][72];
  const int tblk = blockIdx.x, h = blockIdx.y, b = blockIdx.z;
  const int tid = threadIdx.x;
  const ushort_t* src =
      V + (long long)b * sVb + (size_t)(tblk * 64) * ldv + coloff + h * 64;
#pragma unroll
  for (int j = 0; j < 2; ++j) {
    const int c = j * 256 + tid;
    const int r = c >> 3, dc = c & 7;
    *(uint4*)&tile[r][dc * 8] = *(const uint4*)(src + (size_t)r * ldv + dc * 8);
  }
  __syncthreads();
  ushort_t* dst = Vt + (size_t)(b * H_ + h) * 64 * 1024 + tblk * 64;
#pragma unroll
  for (int j = 0; j < 2; ++j) {
    const int c = j * 256 + tid;
    const int d = c >> 3, tc = c & 7;
    union {
      ushort_t u[8];
      uint4 v;
    } t;
#pragma unroll
    for (int i = 0; i < 8; ++i) t.u[i] = tile[tc * 8 + i][d];
    *(uint4*)(dst + (size_t)d * 1024 + tc * 8) = t.v;
  }
}

// ---------------------------------------------------------------------------
// Kernel 7: MFMA flash attention, f16. Output split2-f16.
// ---------------------------------------------------------------------------
__global__ __launch_bounds__(256) void attn_mfma(
    const f16* __restrict__ Qp, long long sQb, int ldq,
    const f16* __restrict__ Kp, long long sKb, int ldk,
    const f16* __restrict__ Vt, f16* __restrict__ Ohi, f16* __restrict__ Olo,
    long long sOb) {
  __shared__ f16 Qs[4096];
  __shared__ f16 Ks[4096];
  __shared__ f16 Vs[4096];
  __shared__ f16 Ps[4096];
  const int tid = threadIdx.x, wave = tid >> 6, lane = tid & 63;
  const int quad = lane >> 4, m16 = lane & 15;
  const int q0 = blockIdx.x * 64, h = blockIdx.y, b = blockIdx.z;
  const f16* Qb = Qp + (long long)b * sQb + h * 64;
  const f16* Kb = Kp + (long long)b * sKb + h * 64;
  const f16* Vb = Vt + (size_t)(b * H_ + h) * 64 * 1024;

#pragma unroll
  for (int j = 0; j < 2; ++j) {
    const int c = j * 256 + wave * 64 + lane;
    gload16(Qb + (size_t)(q0 + (c & 63)) * ldq + (c >> 6) * 8, &Qs[c * 8]);
  }
  float m_run[4], l_run[4];
#pragma unroll
  for (int r = 0; r < 4; ++r) {
    m_run[r] = -1e30f;
    l_run[r] = 0.f;
  }
  f32x4 Oa[4];
  const f32x4 z = {0.f, 0.f, 0.f, 0.f};
#pragma unroll
  for (int j = 0; j < 4; ++j) Oa[j] = z;

  for (int kt = 0; kt < 16; ++kt) {
#pragma unroll
    for (int j = 0; j < 2; ++j) {
      const int c = j * 256 + wave * 64 + lane;
      gload16(Kb + (size_t)(kt * 64 + (c & 63)) * ldk + (c >> 6) * 8,
              &Ks[c * 8]);
      gload16(Vb + (size_t)(c & 63) * 1024 + kt * 64 + (c >> 6) * 8,
              &Vs[c * 8]);
    }
    __syncthreads();
    const f16x8 qf0 = *(const f16x8*)&Qs[(quad * 64 + wave * 16 + m16) * 8];
    const f16x8 qf1 =
        *(const f16x8*)&Qs[((4 + quad) * 64 + wave * 16 + m16) * 8];
    f32x4 S[4];
#pragma unroll
    for (int jn = 0; jn < 4; ++jn) {
      S[jn] = z;
      const f16x8 kf0 = *(const f16x8*)&Ks[(quad * 64 + jn * 16 + m16) * 8];
      const f16x8 kf1 =
          *(const f16x8*)&Ks[((4 + quad) * 64 + jn * 16 + m16) * 8];
      S[jn] = __builtin_amdgcn_mfma_f32_16x16x32_f16(qf0, kf0, S[jn], 0, 0, 0);
      S[jn] = __builtin_amdgcn_mfma_f32_16x16x32_f16(qf1, kf1, S[jn], 0, 0, 0);
    }
#pragma unroll
    for (int jn = 0; jn < 4; ++jn) S[jn] *= 0.125f;
    float mnew[4], al[4], rs[4];
#pragma unroll
    for (int r = 0; r < 4; ++r) {
      float mx = fmaxf(fmaxf(S[0][r], S[1][r]), fmaxf(S[2][r], S[3][r]));
      mx = fmaxf(mx, __shfl_xor(mx, 1, 64));
      mx = fmaxf(mx, __shfl_xor(mx, 2, 64));
      mx = fmaxf(mx, __shfl_xor(mx, 4, 64));
      mx = fmaxf(mx, __shfl_xor(mx, 8, 64));
      mnew[r] = fmaxf(m_run[r], mx);
      al[r] = __expf(m_run[r] - mnew[r]);
      m_run[r] = mnew[r];
      rs[r] = 0.f;
    }
#pragma unroll
    for (int jn = 0; jn < 4; ++jn)
#pragma unroll
      for (int r = 0; r < 4; ++r) {
        const float p = __expf(S[jn][r] - mnew[r]);
        S[jn][r] = p;
        rs[r] += p;
      }
#pragma unroll
    for (int r = 0; r < 4; ++r) {
      float s = rs[r];
      s += __shfl_xor(s, 1, 64);
      s += __shfl_xor(s, 2, 64);
      s += __shfl_xor(s, 4, 64);
      s += __shfl_xor(s, 8, 64);
      l_run[r] = l_run[r] * al[r] + s;
    }
#pragma unroll
    for (int j = 0; j < 4; ++j) {
      Oa[j][0] *= al[0];
      Oa[j][1] *= al[1];
      Oa[j][2] *= al[2];
      Oa[j][3] *= al[3];
    }
    f16* Pw = Ps + wave * 1024;
#pragma unroll
    for (int jn = 0; jn < 4; ++jn)
#pragma unroll
      for (int r = 0; r < 4; ++r)
        Pw[((jn * 2 + (m16 >> 3)) * 16 + quad * 4 + r) * 8 + (m16 & 7)] =
            (f16)S[jn][r];
    const f16x8 pf0 = *(const f16x8*)&Pw[(quad * 16 + m16) * 8];
    const f16x8 pf1 = *(const f16x8*)&Pw[((4 + quad) * 16 + m16) * 8];
#pragma unroll
    for (int jd = 0; jd < 4; ++jd) {
      const f16x8 vf0 = *(const f16x8*)&Vs[(quad * 64 + jd * 16 + m16) * 8];
      const f16x8 vf1 =
          *(const f16x8*)&Vs[((4 + quad) * 64 + jd * 16 + m16) * 8];
      Oa[jd] = __builtin_amdgcn_mfma_f32_16x16x32_f16(pf0, vf0, Oa[jd], 0, 0, 0);
      Oa[jd] = __builtin_amdgcn_mfma_f32_16x16x32_f16(pf1, vf1, Oa[jd], 0, 0, 0);
    }
    __syncthreads();
  }
#pragma unroll
  for (int jd = 0; jd < 4; ++jd)
#pragma unroll
    for (int r = 0; r < 4; ++r) {
      const float v = Oa[jd][r] / l_run[r];
      const f16 hi = (f16)v;
      const f16 lo = (f16)(v - (float)hi);
      const size_t off = (long long)b * sOb +
                         (size_t)(q0 + wave * 16 + quad * 4 + r) * D_ + h * 64 +
                         jd * 16 + m16;
      Ohi[off] = hi;
      Olo[off] = lo;
    }
}

// ---------------------------------------------------------------------------
extern "C" void kernel_launch(void* const* d_in, const int* in_sizes, int n_in,
                              void* d_out, int out_size, void* d_ws,
                              size_t ws_size, hipStream_t stream) {
  const float* x = (const float*)d_in[0];
  const float* coords = (const float*)d_in[1];
  const unsigned char* isctx = (const unsigned char*)d_in[2];
  const float* rope = (const float*)d_in[3];
  const float* ctx_in_w = (const float*)d_in[4];
  const float* ctx_in_b = (const float*)d_in[5];
  const float* ctx_out_w = (const float*)d_in[6];
  const float* ctx_out_b = (const float*)d_in[7];
  const float* tgt_in_w = (const float*)d_in[8];
  const float* tgt_in_b = (const float*)d_in[9];
  const float* tgt_out_w = (const float*)d_in[10];
  const float* tgt_out_b = (const float*)d_in[11];
  float* out = (float*)d_out;

  // ws layout (f16 units): tokhi 8M | toklo 8M | wcat 8M | qkvc 12M | kvt 8M |
  // qt 4M | vt 4M | pos/ipos ints (~109 MB)
  f16* ws = (f16*)d_ws;
  f16* tokhi = ws;
  f16* toklo = tokhi + 8388608;
  f16* wcat = toklo + 8388608;
  f16* qkvc = wcat + 8388608;
  f16* kvt = qkvc + 12582912;
  f16* qt = kvt + 8388608;
  f16* vt = qt + 4194304;
  int* pos = (int*)(vt + 4194304);
  int* ipos = pos + B_ * K_;

  partition_kernel<<<B_, 256, 0, stream>>>(isctx, pos, ipos);
  cvt_all<<<8192, 256, 0, stream>>>(ctx_in_w, tgt_in_w, ctx_out_w, tgt_out_w,
                                    wcat);
  rope_kernel<<<B_ * K_, 256, 0, stream>>>(x, coords, rope, ipos, tokhi, toklo);

  // Merged projection: N=5120 (ctx QKV 3072 | tgt KV 2048), M=1024 ctx rows.
  gemm_proj<<<dim3(40, 8, B_), 256, 0, stream>>>(
      tokhi, toklo, (long long)K_ * D_, wcat, ctx_in_b, tgt_in_b + D_, 3 * D_,
      qkvc, (long long)NCTX_ * 3 * D_, 3 * D_, kvt, (long long)NCTX_ * 2 * D_,
      2 * D_, D_);
  // tgt Q projection: M=1024 tgt rows, N=1024.
  gemm_proj<<<dim3(8, 8, B_), 256, 0, stream>>>(
      tokhi + (size_t)NCTX_ * D_, toklo + (size_t)NCTX_ * D_,
      (long long)K_ * D_, wcat + 5242880, tgt_in_b, tgt_in_b, 1 << 30, qt,
      (long long)NCTX_ * D_, D_, nullptr, 0, 0, D_);

  // ctx self-attention (output overwrites tokhi/toklo rows 0..1023)
  vtrans_kernel<<<dim3(16, H_, B_), 256, 0, stream>>>(
      (const ushort_t*)qkvc, (long long)NCTX_ * 3 * D_, 3 * D_, 2 * D_,
      (ushort_t*)vt);
  attn_mfma<<<dim3(16, H_, B_), 256, 0, stream>>>(
      qkvc, (long long)NCTX_ * 3 * D_, 3 * D_, qkvc + D_,
      (long long)NCTX_ * 3 * D_, 3 * D_, vt, tokhi, toklo, (long long)K_ * D_);
  // tgt cross-attention
  vtrans_kernel<<<dim3(16, H_, B_), 256, 0, stream>>>(
      (const ushort_t*)kvt, (long long)NCTX_ * 2 * D_, 2 * D_, D_,
      (ushort_t*)vt);
  attn_mfma<<<dim3(16, H_, B_), 256, 0, stream>>>(
      qt, (long long)NCTX_ * D_, D_, kvt, (long long)NCTX_ * 2 * D_, 2 * D_,
      vt, tokhi + (size_t)NCTX_ * D_, toklo + (size_t)NCTX_ * D_,
      (long long)K_ * D_);

  // Merged output projections (fp32, scattered to original order)
  gemm_out<<<dim3(8, 8, 2 * B_), 256, 0, stream>>>(
      tokhi, toklo, wcat + 6291456, ctx_out_b, tgt_out_b, ipos, out);
}

// Round 4
// 441.982 us; speedup vs baseline: 5.1081x; 1.1895x over previous
//
#include <hip/hip_runtime.h>
#include <math.h>

#define B_    4
#define K_    2048
#define D_    1024
#define H_    16
#define NCTX_ 1024

typedef unsigned short ushort_t;
typedef _Float16 f16;
typedef __attribute__((ext_vector_type(8))) _Float16 f16x8;
typedef __attribute__((ext_vector_type(4))) float f32x4;

union U4 {
  f16 h[4];
  ushort4 u;
};

__device__ __forceinline__ void gload16(const void* g, void* l) {
  __builtin_amdgcn_global_load_lds(
      (const __attribute__((address_space(1))) unsigned int*)g,
      (__attribute__((address_space(3))) unsigned int*)l, 16, 0, 0);
}

// ---------------------------------------------------------------------------
// Kernel 1: partition scan (verified R1-R3).
// ---------------------------------------------------------------------------
__global__ __launch_bounds__(256) void partition_kernel(
    const unsigned char* __restrict__ isctx, int* __restrict__ pos,
    int* __restrict__ ipos) {
  const int b = blockIdx.x;
  const int tid = threadIdx.x;
  const int wid = tid >> 6, lane = tid & 63;
  __shared__ int csum[4];
  __shared__ int waveTot[4];
  __shared__ int strideSh;

  int cnt = 0;
  for (int i = 0; i < 32; ++i) cnt += (isctx[tid * 32 + i] != 0);
  for (int off = 32; off; off >>= 1) cnt += __shfl_down(cnt, off, 64);
  if (lane == 0) csum[wid] = cnt;
  __syncthreads();
  if (tid == 0) {
    int t = csum[0] + csum[1] + csum[2] + csum[3];
    strideSh = (t > 2048) ? 1 : ((t > 768) ? 4 : 8);
  }
  __syncthreads();
  const int stride = strideSh;

  const unsigned char* base = isctx + (size_t)b * K_ * stride;
  int f[8];
  int s = 0;
  for (int i = 0; i < 8; ++i) {
    f[i] = base[(size_t)(tid * 8 + i) * stride] != 0;
    s += f[i];
  }
  int inc = s;
  for (int off = 1; off < 64; off <<= 1) {
    int v = __shfl_up(inc, off, 64);
    if (lane >= off) inc += v;
  }
  if (lane == 63) waveTot[wid] = inc;
  __syncthreads();
  int wOff = 0;
  for (int w = 0; w < wid; ++w) wOff += waveTot[w];
  int run = wOff + inc - s;
  for (int i = 0; i < 8; ++i) {
    int k = tid * 8 + i;
    int p;
    if (f[i]) {
      p = run;
      run++;
    } else {
      p = NCTX_ + k - run;
    }
    pos[b * K_ + k] = p;
    ipos[b * K_ + p] = k;
  }
}

// ---------------------------------------------------------------------------
// Kernel 2: RoPE + permute-gather -> f16 token buffer.
// ---------------------------------------------------------------------------
__global__ __launch_bounds__(256) void rope_kernel(
    const float* __restrict__ x, const float* __restrict__ coords,
    const float* __restrict__ cache, const int* __restrict__ ipos,
    f16* __restrict__ tok) {
  const int row = blockIdx.x;
  const int b = row >> 11;
  const int r = row & (K_ - 1);
  const int k = ipos[row];
  const int t = threadIdx.x;

  const float cy = coords[(size_t)(b * K_ + k) * 2 + 0];
  const float cx = coords[(size_t)(b * K_ + k) * 2 + 1];
  const int ypos = (int)fminf(fmaxf(cy / 224.0f * 1023.0f, 0.0f), 1023.0f);
  const int xpos = (int)fminf(fmaxf(cx / 224.0f * 1023.0f, 0.0f), 1023.0f);

  const float4 v = ((const float4*)(x + ((size_t)b * K_ + k) * D_))[t];
  const int e = 4 * t;
  const float* crow;
  int coff;
  if (e < 512) {
    crow = cache + (size_t)xpos * 512;
    coff = e;
  } else {
    crow = cache + (size_t)ypos * 512;
    coff = e - 512;
  }
  const float4 cs = *(const float4*)(crow + coff);
  float o[4];
  o[0] = v.x * cs.x - v.y * cs.y;
  o[1] = v.x * cs.y + v.y * cs.x;
  o[2] = v.z * cs.z - v.w * cs.w;
  o[3] = v.z * cs.w + v.w * cs.z;
  U4 h;
#pragma unroll
  for (int i = 0; i < 4; ++i) h.h[i] = (f16)o[i];
  ((ushort4*)(tok + ((size_t)b * K_ + r) * D_))[t] = h.u;
}

// ---------------------------------------------------------------------------
// Kernel 3: all weights fp32 -> f16, concatenated:
// [0,3M) ctx_in | [3M,5M) tgt_in kv | [5M,6M) tgt_in q | [6M,7M) ctx_out |
// [7M,8M) tgt_out   (M = 1048576 floats)
// ---------------------------------------------------------------------------
__global__ __launch_bounds__(256) void cvt_all(
    const float* __restrict__ ctx_in_w, const float* __restrict__ tgt_in_w,
    const float* __restrict__ ctx_out_w, const float* __restrict__ tgt_out_w,
    f16* __restrict__ dst) {
  const int i4 = blockIdx.x * 256 + threadIdx.x;  // 0..2097151
  const int f = i4 * 4;
  const float* src;
  if (f < 3145728) src = ctx_in_w + f;
  else if (f < 5242880) src = tgt_in_w + (f - 3145728 + 1048576);
  else if (f < 6291456) src = tgt_in_w + (f - 5242880);
  else if (f < 7340032) src = ctx_out_w + (f - 6291456);
  else src = tgt_out_w + (f - 7340032);
  const float4 v = *(const float4*)src;
  U4 u;
  u.h[0] = (f16)v.x;
  u.h[1] = (f16)v.y;
  u.h[2] = (f16)v.z;
  u.h[3] = (f16)v.w;
  ((ushort4*)dst)[i4] = u.u;
}

// ---------------------------------------------------------------------------
// GEMM core: C[m][n] = sum_k A[m][k] * W[n][k], f16 MFMA, fp32 acc.
// 128x128x32 tile, 4 waves, 1 MFMA per 16x16 sub-tile per K-step (m97 shape).
// ---------------------------------------------------------------------------
#define GEMM_CORE(AP, WP, Kd)                                                 \
  f32x4 acc[4][4];                                                            \
  {                                                                           \
    const f32x4 z = {0.f, 0.f, 0.f, 0.f};                                     \
    for (int i = 0; i < 4; ++i)                                               \
      for (int j = 0; j < 4; ++j) acc[i][j] = z;                              \
  }                                                                           \
  for (int k0 = 0; k0 < Kd; k0 += 32) {                                       \
    _Pragma("unroll") for (int j = 0; j < 4; ++j) {                           \
      const int t = j >> 1;                                                   \
      const int c = ((j & 1) * 4 + wave) * 64 + lane;                         \
      const int q = c >> 7, r = c & 127;                                      \
      const f16* g = (t == 0) ? (AP + (size_t)(m0 + r) * Kd + k0 + q * 8)     \
                              : (WP + (size_t)(n0 + r) * Kd + k0 + q * 8);    \
      gload16(g, &lds[t * 4096 + c * 8]);                                     \
    }                                                                         \
    __syncthreads();                                                          \
    f16x8 af[4], wf[4];                                                       \
    _Pragma("unroll") for (int i = 0; i < 4; ++i) {                           \
      af[i] = *(const f16x8*)&lds[(quad * 128 + wm + i * 16 + m16) * 8];      \
      wf[i] = *(const f16x8*)&lds[4096 + (quad * 128 + wn + i * 16 + m16) * 8];\
    }                                                                         \
    _Pragma("unroll") for (int i = 0; i < 4; ++i)                             \
        _Pragma("unroll") for (int j = 0; j < 4; ++j) {                       \
      acc[i][j] =                                                             \
          __builtin_amdgcn_mfma_f32_16x16x32_f16(af[i], wf[j], acc[i][j], 0,  \
                                                 0, 0);                       \
    }                                                                         \
    __syncthreads();                                                          \
  }

// ---------------------------------------------------------------------------
// Kernel 4: projection GEMM, f16 output split across two destinations at
// column colSplit (D0: ldc0, D1: ldc1). bias1 indexed by (col - colSplit).
// ---------------------------------------------------------------------------
__global__ __launch_bounds__(256) void gemm_proj(
    const f16* __restrict__ A, long long sAb, const f16* __restrict__ W,
    const float* __restrict__ bias0, const float* __restrict__ bias1,
    int colSplit, f16* __restrict__ D0, long long sD0b, int ldc0,
    f16* __restrict__ D1, long long sD1b, int ldc1, int Kd) {
  __shared__ f16 lds[8192];
  const int tid = threadIdx.x;
  const int wave = tid >> 6, lane = tid & 63;
  const int quad = lane >> 4, m16 = lane & 15;
  const int n0 = blockIdx.x * 128, m0 = blockIdx.y * 128, b = blockIdx.z;
  const int wm = (wave & 1) << 6, wn = (wave >> 1) << 6;
  const f16* AB = A + (long long)b * sAb;

  GEMM_CORE(AB, W, Kd)

#pragma unroll
  for (int j = 0; j < 4; ++j) {
    const int col = n0 + wn + j * 16 + m16;
    const float bv = (col < colSplit) ? bias0[col] : bias1[col - colSplit];
#pragma unroll
    for (int i = 0; i < 4; ++i) {
      const int mr = m0 + wm + i * 16 + quad * 4;
#pragma unroll
      for (int r = 0; r < 4; ++r) {
        const float v = acc[i][j][r] + bv;
        if (col < colSplit)
          D0[(long long)b * sD0b + (size_t)(mr + r) * ldc0 + col] = (f16)v;
        else
          D1[(long long)b * sD1b + (size_t)(mr + r) * ldc1 + col - colSplit] =
              (f16)v;
      }
    }
  }
}

// ---------------------------------------------------------------------------
// Kernel 5: merged output projections. b = z&3, sel = z>>2.
// fp32 output scattered to original token order.
// ---------------------------------------------------------------------------
__global__ __launch_bounds__(256) void gemm_out(
    const f16* __restrict__ Atok, const f16* __restrict__ Wbase,
    const float* __restrict__ bias_ctx, const float* __restrict__ bias_tgt,
    const int* __restrict__ ipos, float* __restrict__ out) {
  __shared__ f16 lds[8192];
  const int tid = threadIdx.x;
  const int wave = tid >> 6, lane = tid & 63;
  const int quad = lane >> 4, m16 = lane & 15;
  const int n0 = blockIdx.x * 128, m0 = blockIdx.y * 128;
  const int b = blockIdx.z & 3, sel = blockIdx.z >> 2;
  const int wm = (wave & 1) << 6, wn = (wave >> 1) << 6;
  const f16* AB = Atok + (size_t)b * K_ * D_ + (size_t)sel * NCTX_ * D_;
  const f16* W = Wbase + (size_t)sel * 1048576;
  const float* bias = sel ? bias_tgt : bias_ctx;

  GEMM_CORE(AB, W, D_)

#pragma unroll
  for (int j = 0; j < 4; ++j) {
    const int col = n0 + wn + j * 16 + m16;
    const float bv = bias[col];
#pragma unroll
    for (int i = 0; i < 4; ++i) {
      const int mr = m0 + wm + i * 16 + quad * 4;
#pragma unroll
      for (int r = 0; r < 4; ++r) {
        const int orow = ipos[b * K_ + sel * NCTX_ + mr + r];
        out[(size_t)b * K_ * D_ + (size_t)orow * D_ + col] =
            acc[i][j][r] + bv;
      }
    }
  }
}

// ---------------------------------------------------------------------------
// Kernel 6: V transpose (16-bit moves).
// ---------------------------------------------------------------------------
__global__ __launch_bounds__(256) void vtrans_kernel(
    const ushort_t* __restrict__ V, long long sVb, int ldv, int coloff,
    ushort_t* __restrict__ Vt) {
  __shared__ __align__(16) ushort_t tile[64][72];
  const int tblk = blockIdx.x, h = blockIdx.y, b = blockIdx.z;
  const int tid = threadIdx.x;
  const ushort_t* src =
      V + (long long)b * sVb + (size_t)(tblk * 64) * ldv + coloff + h * 64;
#pragma unroll
  for (int j = 0; j < 2; ++j) {
    const int c = j * 256 + tid;
    const int r = c >> 3, dc = c & 7;
    *(uint4*)&tile[r][dc * 8] = *(const uint4*)(src + (size_t)r * ldv + dc * 8);
  }
  __syncthreads();
  ushort_t* dst = Vt + (size_t)(b * H_ + h) * 64 * 1024 + tblk * 64;
#pragma unroll
  for (int j = 0; j < 2; ++j) {
    const int c = j * 256 + tid;
    const int d = c >> 3, tc = c & 7;
    union {
      ushort_t u[8];
      uint4 v;
    } t;
#pragma unroll
    for (int i = 0; i < 8; ++i) t.u[i] = tile[tc * 8 + i][d];
    *(uint4*)(dst + (size_t)d * 1024 + tc * 8) = t.v;
  }
}

// ---------------------------------------------------------------------------
// Kernel 7: MFMA flash attention, f16, single-f16 output.
// ---------------------------------------------------------------------------
__global__ __launch_bounds__(256) void attn_mfma(
    const f16* __restrict__ Qp, long long sQb, int ldq,
    const f16* __restrict__ Kp, long long sKb, int ldk,
    const f16* __restrict__ Vt, f16* __restrict__ O, long long sOb) {
  __shared__ f16 Qs[4096];
  __shared__ f16 Ks[4096];
  __shared__ f16 Vs[4096];
  __shared__ f16 Ps[4096];
  const int tid = threadIdx.x, wave = tid >> 6, lane = tid & 63;
  const int quad = lane >> 4, m16 = lane & 15;
  const int q0 = blockIdx.x * 64, h = blockIdx.y, b = blockIdx.z;
  const f16* Qb = Qp + (long long)b * sQb + h * 64;
  const f16* Kb = Kp + (long long)b * sKb + h * 64;
  const f16* Vb = Vt + (size_t)(b * H_ + h) * 64 * 1024;

#pragma unroll
  for (int j = 0; j < 2; ++j) {
    const int c = j * 256 + wave * 64 + lane;
    gload16(Qb + (size_t)(q0 + (c & 63)) * ldq + (c >> 6) * 8, &Qs[c * 8]);
  }
  float m_run[4], l_run[4];
#pragma unroll
  for (int r = 0; r < 4; ++r) {
    m_run[r] = -1e30f;
    l_run[r] = 0.f;
  }
  f32x4 Oa[4];
  const f32x4 z = {0.f, 0.f, 0.f, 0.f};
#pragma unroll
  for (int j = 0; j < 4; ++j) Oa[j] = z;

  for (int kt = 0; kt < 16; ++kt) {
#pragma unroll
    for (int j = 0; j < 2; ++j) {
      const int c = j * 256 + wave * 64 + lane;
      gload16(Kb + (size_t)(kt * 64 + (c & 63)) * ldk + (c >> 6) * 8,
              &Ks[c * 8]);
      gload16(Vb + (size_t)(c & 63) * 1024 + kt * 64 + (c >> 6) * 8,
              &Vs[c * 8]);
    }
    __syncthreads();
    const f16x8 qf0 = *(const f16x8*)&Qs[(quad * 64 + wave * 16 + m16) * 8];
    const f16x8 qf1 =
        *(const f16x8*)&Qs[((4 + quad) * 64 + wave * 16 + m16) * 8];
    f32x4 S[4];
#pragma unroll
    for (int jn = 0; jn < 4; ++jn) {
      S[jn] = z;
      const f16x8 kf0 = *(const f16x8*)&Ks[(quad * 64 + jn * 16 + m16) * 8];
      const f16x8 kf1 =
          *(const f16x8*)&Ks[((4 + quad) * 64 + jn * 16 + m16) * 8];
      S[jn] = __builtin_amdgcn_mfma_f32_16x16x32_f16(qf0, kf0, S[jn], 0, 0, 0);
      S[jn] = __builtin_amdgcn_mfma_f32_16x16x32_f16(qf1, kf1, S[jn], 0, 0, 0);
    }
#pragma unroll
    for (int jn = 0; jn < 4; ++jn) S[jn] *= 0.125f;
    float mnew[4], al[4], rs[4];
#pragma unroll
    for (int r = 0; r < 4; ++r) {
      float mx = fmaxf(fmaxf(S[0][r], S[1][r]), fmaxf(S[2][r], S[3][r]));
      mx = fmaxf(mx, __shfl_xor(mx, 1, 64));
      mx = fmaxf(mx, __shfl_xor(mx, 2, 64));
      mx = fmaxf(mx, __shfl_xor(mx, 4, 64));
      mx = fmaxf(mx, __shfl_xor(mx, 8, 64));
      mnew[r] = fmaxf(m_run[r], mx);
      al[r] = __expf(m_run[r] - mnew[r]);
      m_run[r] = mnew[r];
      rs[r] = 0.f;
    }
#pragma unroll
    for (int jn = 0; jn < 4; ++jn)
#pragma unroll
      for (int r = 0; r < 4; ++r) {
        const float p = __expf(S[jn][r] - mnew[r]);
        S[jn][r] = p;
        rs[r] += p;
      }
#pragma unroll
    for (int r = 0; r < 4; ++r) {
      float s = rs[r];
      s += __shfl_xor(s, 1, 64);
      s += __shfl_xor(s, 2, 64);
      s += __shfl_xor(s, 4, 64);
      s += __shfl_xor(s, 8, 64);
      l_run[r] = l_run[r] * al[r] + s;
    }
#pragma unroll
    for (int j = 0; j < 4; ++j) {
      Oa[j][0] *= al[0];
      Oa[j][1] *= al[1];
      Oa[j][2] *= al[2];
      Oa[j][3] *= al[3];
    }
    f16* Pw = Ps + wave * 1024;
#pragma unroll
    for (int jn = 0; jn < 4; ++jn)
#pragma unroll
      for (int r = 0; r < 4; ++r)
        Pw[((jn * 2 + (m16 >> 3)) * 16 + quad * 4 + r) * 8 + (m16 & 7)] =
            (f16)S[jn][r];
    const f16x8 pf0 = *(const f16x8*)&Pw[(quad * 16 + m16) * 8];
    const f16x8 pf1 = *(const f16x8*)&Pw[((4 + quad) * 16 + m16) * 8];
#pragma unroll
    for (int jd = 0; jd < 4; ++jd) {
      const f16x8 vf0 = *(const f16x8*)&Vs[(quad * 64 + jd * 16 + m16) * 8];
      const f16x8 vf1 =
          *(const f16x8*)&Vs[((4 + quad) * 64 + jd * 16 + m16) * 8];
      Oa[jd] = __builtin_amdgcn_mfma_f32_16x16x32_f16(pf0, vf0, Oa[jd], 0, 0, 0);
      Oa[jd] = __builtin_amdgcn_mfma_f32_16x16x32_f16(pf1, vf1, Oa[jd], 0, 0, 0);
    }
    __syncthreads();
  }
#pragma unroll
  for (int jd = 0; jd < 4; ++jd)
#pragma unroll
    for (int r = 0; r < 4; ++r) {
      const float v = Oa[jd][r] / l_run[r];
      const size_t off = (long long)b * sOb +
                         (size_t)(q0 + wave * 16 + quad * 4 + r) * D_ + h * 64 +
                         jd * 16 + m16;
      O[off] = (f16)v;
    }
}

// ---------------------------------------------------------------------------
extern "C" void kernel_launch(void* const* d_in, const int* in_sizes, int n_in,
                              void* d_out, int out_size, void* d_ws,
                              size_t ws_size, hipStream_t stream) {
  const float* x = (const float*)d_in[0];
  const float* coords = (const float*)d_in[1];
  const unsigned char* isctx = (const unsigned char*)d_in[2];
  const float* rope = (const float*)d_in[3];
  const float* ctx_in_w = (const float*)d_in[4];
  const float* ctx_in_b = (const float*)d_in[5];
  const float* ctx_out_w = (const float*)d_in[6];
  const float* ctx_out_b = (const float*)d_in[7];
  const float* tgt_in_w = (const float*)d_in[8];
  const float* tgt_in_b = (const float*)d_in[9];
  const float* tgt_out_w = (const float*)d_in[10];
  const float* tgt_out_b = (const float*)d_in[11];
  float* out = (float*)d_out;

  // ws layout (f16 units): tok 8M | wcat 8M | qkvc 12M | kvt 8M | qt 4M |
  // vt 4M | pos/ipos ints (~92 MB)
  f16* ws = (f16*)d_ws;
  f16* tok = ws;
  f16* wcat = tok + 8388608;
  f16* qkvc = wcat + 8388608;
  f16* kvt = qkvc + 12582912;
  f16* qt = kvt + 8388608;
  f16* vt = qt + 4194304;
  int* pos = (int*)(vt + 4194304);
  int* ipos = pos + B_ * K_;

  partition_kernel<<<B_, 256, 0, stream>>>(isctx, pos, ipos);
  cvt_all<<<8192, 256, 0, stream>>>(ctx_in_w, tgt_in_w, ctx_out_w, tgt_out_w,
                                    wcat);
  rope_kernel<<<B_ * K_, 256, 0, stream>>>(x, coords, rope, ipos, tok);

  // Merged projection: N=5120 (ctx QKV 3072 | tgt KV 2048), M=1024 ctx rows.
  gemm_proj<<<dim3(40, 8, B_), 256, 0, stream>>>(
      tok, (long long)K_ * D_, wcat, ctx_in_b, tgt_in_b + D_, 3 * D_, qkvc,
      (long long)NCTX_ * 3 * D_, 3 * D_, kvt, (long long)NCTX_ * 2 * D_,
      2 * D_, D_);
  // tgt Q projection: M=1024 tgt rows, N=1024.
  gemm_proj<<<dim3(8, 8, B_), 256, 0, stream>>>(
      tok + (size_t)NCTX_ * D_, (long long)K_ * D_, wcat + 5242880, tgt_in_b,
      tgt_in_b, 1 << 30, qt, (long long)NCTX_ * D_, D_, nullptr, 0, 0, D_);

  // ctx self-attention (output overwrites tok rows 0..1023)
  vtrans_kernel<<<dim3(16, H_, B_), 256, 0, stream>>>(
      (const ushort_t*)qkvc, (long long)NCTX_ * 3 * D_, 3 * D_, 2 * D_,
      (ushort_t*)vt);
  attn_mfma<<<dim3(16, H_, B_), 256, 0, stream>>>(
      qkvc, (long long)NCTX_ * 3 * D_, 3 * D_, qkvc + D_,
      (long long)NCTX_ * 3 * D_, 3 * D_, vt, tok, (long long)K_ * D_);
  // tgt cross-attention
  vtrans_kernel<<<dim3(16, H_, B_), 256, 0, stream>>>(
      (const ushort_t*)kvt, (long long)NCTX_ * 2 * D_, 2 * D_, D_,
      (ushort_t*)vt);
  attn_mfma<<<dim3(16, H_, B_), 256, 0, stream>>>(
      qt, (long long)NCTX_ * D_, D_, kvt, (long long)NCTX_ * 2 * D_, 2 * D_,
      vt, tok + (size_t)NCTX_ * D_, (long long)K_ * D_);

  // Merged output projections (fp32, scattered to original order)
  gemm_out<<<dim3(8, 8, 2 * B_), 256, 0, stream>>>(
      tok, wcat + 6291456, ctx_out_b, tgt_out_b, ipos, out);
}

// Round 5
// 421.424 us; speedup vs baseline: 5.3573x; 1.0488x over previous
//
#include <hip/hip_runtime.h>
#include <math.h>

#define B_    4
#define K_    2048
#define D_    1024
#define H_    16
#define NCTX_ 1024

typedef unsigned short ushort_t;
typedef _Float16 f16;
typedef __attribute__((ext_vector_type(8))) _Float16 f16x8;
typedef __attribute__((ext_vector_type(4))) float f32x4;

union U4 {
  f16 h[4];
  ushort4 u;
};

__device__ __forceinline__ void gload16(const void* g, void* l) {
  __builtin_amdgcn_global_load_lds(
      (const __attribute__((address_space(1))) unsigned int*)g,
      (__attribute__((address_space(3))) unsigned int*)l, 16, 0, 0);
}

// ---------------------------------------------------------------------------
// Kernel 1: partition scan (verified R1-R4).
// ---------------------------------------------------------------------------
__global__ __launch_bounds__(256) void partition_kernel(
    const unsigned char* __restrict__ isctx, int* __restrict__ pos,
    int* __restrict__ ipos) {
  const int b = blockIdx.x;
  const int tid = threadIdx.x;
  const int wid = tid >> 6, lane = tid & 63;
  __shared__ int csum[4];
  __shared__ int waveTot[4];
  __shared__ int strideSh;

  int cnt = 0;
  for (int i = 0; i < 32; ++i) cnt += (isctx[tid * 32 + i] != 0);
  for (int off = 32; off; off >>= 1) cnt += __shfl_down(cnt, off, 64);
  if (lane == 0) csum[wid] = cnt;
  __syncthreads();
  if (tid == 0) {
    int t = csum[0] + csum[1] + csum[2] + csum[3];
    strideSh = (t > 2048) ? 1 : ((t > 768) ? 4 : 8);
  }
  __syncthreads();
  const int stride = strideSh;

  const unsigned char* base = isctx + (size_t)b * K_ * stride;
  int f[8];
  int s = 0;
  for (int i = 0; i < 8; ++i) {
    f[i] = base[(size_t)(tid * 8 + i) * stride] != 0;
    s += f[i];
  }
  int inc = s;
  for (int off = 1; off < 64; off <<= 1) {
    int v = __shfl_up(inc, off, 64);
    if (lane >= off) inc += v;
  }
  if (lane == 63) waveTot[wid] = inc;
  __syncthreads();
  int wOff = 0;
  for (int w = 0; w < wid; ++w) wOff += waveTot[w];
  int run = wOff + inc - s;
  for (int i = 0; i < 8; ++i) {
    int k = tid * 8 + i;
    int p;
    if (f[i]) {
      p = run;
      run++;
    } else {
      p = NCTX_ + k - run;
    }
    pos[b * K_ + k] = p;
    ipos[b * K_ + p] = k;
  }
}

// ---------------------------------------------------------------------------
// Kernel 2: RoPE + permute-gather -> f16 token buffer.
// ---------------------------------------------------------------------------
__global__ __launch_bounds__(256) void rope_kernel(
    const float* __restrict__ x, const float* __restrict__ coords,
    const float* __restrict__ cache, const int* __restrict__ ipos,
    f16* __restrict__ tok) {
  const int row = blockIdx.x;
  const int b = row >> 11;
  const int r = row & (K_ - 1);
  const int k = ipos[row];
  const int t = threadIdx.x;

  const float cy = coords[(size_t)(b * K_ + k) * 2 + 0];
  const float cx = coords[(size_t)(b * K_ + k) * 2 + 1];
  const int ypos = (int)fminf(fmaxf(cy / 224.0f * 1023.0f, 0.0f), 1023.0f);
  const int xpos = (int)fminf(fmaxf(cx / 224.0f * 1023.0f, 0.0f), 1023.0f);

  const float4 v = ((const float4*)(x + ((size_t)b * K_ + k) * D_))[t];
  const int e = 4 * t;
  const float* crow;
  int coff;
  if (e < 512) {
    crow = cache + (size_t)xpos * 512;
    coff = e;
  } else {
    crow = cache + (size_t)ypos * 512;
    coff = e - 512;
  }
  const float4 cs = *(const float4*)(crow + coff);
  float o[4];
  o[0] = v.x * cs.x - v.y * cs.y;
  o[1] = v.x * cs.y + v.y * cs.x;
  o[2] = v.z * cs.z - v.w * cs.w;
  o[3] = v.z * cs.w + v.w * cs.z;
  U4 h;
#pragma unroll
  for (int i = 0; i < 4; ++i) h.h[i] = (f16)o[i];
  ((ushort4*)(tok + ((size_t)b * K_ + r) * D_))[t] = h.u;
}

// ---------------------------------------------------------------------------
// Kernel 3: all weights fp32 -> f16, concatenated:
// [0,3M) ctx_in | [3M,5M) tgt_in kv | [5M,6M) tgt_in q | [6M,7M) ctx_out |
// [7M,8M) tgt_out   (M = 1048576 floats)
// ---------------------------------------------------------------------------
__global__ __launch_bounds__(256) void cvt_all(
    const float* __restrict__ ctx_in_w, const float* __restrict__ tgt_in_w,
    const float* __restrict__ ctx_out_w, const float* __restrict__ tgt_out_w,
    f16* __restrict__ dst) {
  const int i4 = blockIdx.x * 256 + threadIdx.x;  // 0..2097151
  const int f = i4 * 4;
  const float* src;
  if (f < 3145728) src = ctx_in_w + f;
  else if (f < 5242880) src = tgt_in_w + (f - 3145728 + 1048576);
  else if (f < 6291456) src = tgt_in_w + (f - 5242880);
  else if (f < 7340032) src = ctx_out_w + (f - 6291456);
  else src = tgt_out_w + (f - 7340032);
  const float4 v = *(const float4*)src;
  U4 u;
  u.h[0] = (f16)v.x;
  u.h[1] = (f16)v.y;
  u.h[2] = (f16)v.z;
  u.h[3] = (f16)v.w;
  ((ushort4*)dst)[i4] = u.u;
}

// ---------------------------------------------------------------------------
// GEMM core, BK=64: C[m][n] = sum_k A[m][k] * W[n][k], f16 MFMA, fp32 acc.
// 128x128x64 tile, 4 waves, 32 MFMA per wave between barrier pairs
// (halves the vmcnt(0)+barrier drain count vs BK=32). AP/WP pre-offset to
// the block's m0/n0 rows. LDS 32 KB -> up to 5 blocks/CU.
// ---------------------------------------------------------------------------
#define GEMM_CORE64(AP, WP, Kd)                                               \
  f32x4 acc[4][4];                                                            \
  {                                                                           \
    const f32x4 z = {0.f, 0.f, 0.f, 0.f};                                     \
    for (int i = 0; i < 4; ++i)                                               \
      for (int j = 0; j < 4; ++j) acc[i][j] = z;                              \
  }                                                                           \
  for (int k0 = 0; k0 < Kd; k0 += 64) {                                       \
    _Pragma("unroll") for (int j = 0; j < 8; ++j) {                           \
      const int c = ((j & 3) * 4 + wave) * 64 + lane;                         \
      const int q = c >> 7, r = c & 127;                                      \
      const f16* g = (j < 4) ? (AP + (size_t)r * Kd + k0 + q * 8)             \
                             : (WP + (size_t)r * Kd + k0 + q * 8);            \
      gload16(g, &lds[(j >> 2) * 8192 + c * 8]);                              \
    }                                                                         \
    __syncthreads();                                                          \
    _Pragma("unroll") for (int kh = 0; kh < 2; ++kh) {                        \
      f16x8 af[4], wf[4];                                                     \
      _Pragma("unroll") for (int i = 0; i < 4; ++i) {                         \
        af[i] = *(const f16x8*)&lds[((kh * 4 + quad) * 128 + wm + i * 16 +    \
                                     m16) * 8];                               \
        wf[i] = *(const f16x8*)&lds[8192 + ((kh * 4 + quad) * 128 + wn +      \
                                            i * 16 + m16) * 8];               \
      }                                                                       \
      _Pragma("unroll") for (int i = 0; i < 4; ++i)                           \
          _Pragma("unroll") for (int j = 0; j < 4; ++j)                       \
        acc[i][j] = __builtin_amdgcn_mfma_f32_16x16x32_f16(                   \
            af[i], wf[j], acc[i][j], 0, 0, 0);                                \
    }                                                                         \
    __syncthreads();                                                          \
  }

// ---------------------------------------------------------------------------
// Kernel 4: merged projection GEMM. grid (48, 8, 4):
//   nb < 40: ctx rows x [ctx_in QKV (3072) | tgt_in KV (2048)] -> qkvc / kvt
//   nb >= 40: tgt rows x tgt_in Q (1024) -> qt
// ---------------------------------------------------------------------------
__global__ __launch_bounds__(256) void gemm_proj(
    const f16* __restrict__ tok, const f16* __restrict__ wcat,
    const float* __restrict__ ctx_in_b, const float* __restrict__ tgt_in_b,
    f16* __restrict__ qkvc, f16* __restrict__ kvt, f16* __restrict__ qt) {
  __shared__ f16 lds[16384];
  const int tid = threadIdx.x;
  const int wave = tid >> 6, lane = tid & 63;
  const int quad = lane >> 4, m16 = lane & 15;
  const int nb = blockIdx.x, mb = blockIdx.y, b = blockIdx.z;
  const int wm = (wave & 1) << 6, wn = (wave >> 1) << 6;
  const int m0 = mb * 128;
  const bool isQ = nb >= 40;
  const int n0 = isQ ? (nb - 40) * 128 : nb * 128;
  const f16* AP = tok + (size_t)b * K_ * D_ +
                  (isQ ? (size_t)NCTX_ * D_ : (size_t)0) + (size_t)m0 * D_;
  const f16* WP = wcat + (isQ ? (size_t)5242880 : (size_t)0) +
                  (size_t)n0 * D_;

  GEMM_CORE64(AP, WP, D_)

#pragma unroll
  for (int j = 0; j < 4; ++j) {
    const int col = n0 + wn + j * 16 + m16;
    float bv;
    f16* dst;
    int ldc, dcol;
    if (isQ) {
      bv = tgt_in_b[col];
      dst = qt + (size_t)b * NCTX_ * D_;
      ldc = D_;
      dcol = col;
    } else if (col < 3072) {
      bv = ctx_in_b[col];
      dst = qkvc + (size_t)b * NCTX_ * 3072;
      ldc = 3072;
      dcol = col;
    } else {
      bv = tgt_in_b[D_ + col - 3072];
      dst = kvt + (size_t)b * NCTX_ * 2048;
      ldc = 2048;
      dcol = col - 3072;
    }
#pragma unroll
    for (int i = 0; i < 4; ++i) {
      const int mr = m0 + wm + i * 16 + quad * 4;
#pragma unroll
      for (int r = 0; r < 4; ++r)
        dst[(size_t)(mr + r) * ldc + dcol] = (f16)(acc[i][j][r] + bv);
    }
  }
}

// ---------------------------------------------------------------------------
// Kernel 5: merged output projections. grid (8, 8, 8): b = z&3, sel = z>>2.
// fp32 output scattered to original token order (16-lane 64B segments ->
// already fully coalesced).
// ---------------------------------------------------------------------------
__global__ __launch_bounds__(256) void gemm_out(
    const f16* __restrict__ Atok, const f16* __restrict__ Wbase,
    const float* __restrict__ bias_ctx, const float* __restrict__ bias_tgt,
    const int* __restrict__ ipos, float* __restrict__ out) {
  __shared__ f16 lds[16384];
  const int tid = threadIdx.x;
  const int wave = tid >> 6, lane = tid & 63;
  const int quad = lane >> 4, m16 = lane & 15;
  const int n0 = blockIdx.x * 128, m0 = blockIdx.y * 128;
  const int b = blockIdx.z & 3, sel = blockIdx.z >> 2;
  const int wm = (wave & 1) << 6, wn = (wave >> 1) << 6;
  const f16* AP = Atok + (size_t)b * K_ * D_ + (size_t)sel * NCTX_ * D_ +
                  (size_t)m0 * D_;
  const f16* WP = Wbase + (size_t)sel * 1048576 + (size_t)n0 * D_;
  const float* bias = sel ? bias_tgt : bias_ctx;

  GEMM_CORE64(AP, WP, D_)

#pragma unroll
  for (int j = 0; j < 4; ++j) {
    const int col = n0 + wn + j * 16 + m16;
    const float bv = bias[col];
#pragma unroll
    for (int i = 0; i < 4; ++i) {
      const int mr = m0 + wm + i * 16 + quad * 4;
#pragma unroll
      for (int r = 0; r < 4; ++r) {
        const int orow = ipos[b * K_ + sel * NCTX_ + mr + r];
        out[(size_t)b * K_ * D_ + (size_t)orow * D_ + col] =
            acc[i][j][r] + bv;
      }
    }
  }
}

// ---------------------------------------------------------------------------
// Kernel 6: V transpose (16-bit moves).
// ---------------------------------------------------------------------------
__global__ __launch_bounds__(256) void vtrans_kernel(
    const ushort_t* __restrict__ V, long long sVb, int ldv, int coloff,
    ushort_t* __restrict__ Vt) {
  __shared__ __align__(16) ushort_t tile[64][72];
  const int tblk = blockIdx.x, h = blockIdx.y, b = blockIdx.z;
  const int tid = threadIdx.x;
  const ushort_t* src =
      V + (long long)b * sVb + (size_t)(tblk * 64) * ldv + coloff + h * 64;
#pragma unroll
  for (int j = 0; j < 2; ++j) {
    const int c = j * 256 + tid;
    const int r = c >> 3, dc = c & 7;
    *(uint4*)&tile[r][dc * 8] = *(const uint4*)(src + (size_t)r * ldv + dc * 8);
  }
  __syncthreads();
  ushort_t* dst = Vt + (size_t)(b * H_ + h) * 64 * 1024 + tblk * 64;
#pragma unroll
  for (int j = 0; j < 2; ++j) {
    const int c = j * 256 + tid;
    const int d = c >> 3, tc = c & 7;
    union {
      ushort_t u[8];
      uint4 v;
    } t;
#pragma unroll
    for (int i = 0; i < 8; ++i) t.u[i] = tile[tc * 8 + i][d];
    *(uint4*)(dst + (size_t)d * 1024 + tc * 8) = t.v;
  }
}

// ---------------------------------------------------------------------------
// Kernel 7: MFMA flash attention, f16, single-f16 output (verified R4).
// ---------------------------------------------------------------------------
__global__ __launch_bounds__(256) void attn_mfma(
    const f16* __restrict__ Qp, long long sQb, int ldq,
    const f16* __restrict__ Kp, long long sKb, int ldk,
    const f16* __restrict__ Vt, f16* __restrict__ O, long long sOb) {
  __shared__ f16 Qs[4096];
  __shared__ f16 Ks[4096];
  __shared__ f16 Vs[4096];
  __shared__ f16 Ps[4096];
  const int tid = threadIdx.x, wave = tid >> 6, lane = tid & 63;
  const int quad = lane >> 4, m16 = lane & 15;
  const int q0 = blockIdx.x * 64, h = blockIdx.y, b = blockIdx.z;
  const f16* Qb = Qp + (long long)b * sQb + h * 64;
  const f16* Kb = Kp + (long long)b * sKb + h * 64;
  const f16* Vb = Vt + (size_t)(b * H_ + h) * 64 * 1024;

#pragma unroll
  for (int j = 0; j < 2; ++j) {
    const int c = j * 256 + wave * 64 + lane;
    gload16(Qb + (size_t)(q0 + (c & 63)) * ldq + (c >> 6) * 8, &Qs[c * 8]);
  }
  float m_run[4], l_run[4];
#pragma unroll
  for (int r = 0; r < 4; ++r) {
    m_run[r] = -1e30f;
    l_run[r] = 0.f;
  }
  f32x4 Oa[4];
  const f32x4 z = {0.f, 0.f, 0.f, 0.f};
#pragma unroll
  for (int j = 0; j < 4; ++j) Oa[j] = z;

  for (int kt = 0; kt < 16; ++kt) {
#pragma unroll
    for (int j = 0; j < 2; ++j) {
      const int c = j * 256 + wave * 64 + lane;
      gload16(Kb + (size_t)(kt * 64 + (c & 63)) * ldk + (c >> 6) * 8,
              &Ks[c * 8]);
      gload16(Vb + (size_t)(c & 63) * 1024 + kt * 64 + (c >> 6) * 8,
              &Vs[c * 8]);
    }
    __syncthreads();
    const f16x8 qf0 = *(const f16x8*)&Qs[(quad * 64 + wave * 16 + m16) * 8];
    const f16x8 qf1 =
        *(const f16x8*)&Qs[((4 + quad) * 64 + wave * 16 + m16) * 8];
    f32x4 S[4];
#pragma unroll
    for (int jn = 0; jn < 4; ++jn) {
      S[jn] = z;
      const f16x8 kf0 = *(const f16x8*)&Ks[(quad * 64 + jn * 16 + m16) * 8];
      const f16x8 kf1 =
          *(const f16x8*)&Ks[((4 + quad) * 64 + jn * 16 + m16) * 8];
      S[jn] = __builtin_amdgcn_mfma_f32_16x16x32_f16(qf0, kf0, S[jn], 0, 0, 0);
      S[jn] = __builtin_amdgcn_mfma_f32_16x16x32_f16(qf1, kf1, S[jn], 0, 0, 0);
    }
#pragma unroll
    for (int jn = 0; jn < 4; ++jn) S[jn] *= 0.125f;
    float mnew[4], al[4], rs[4];
#pragma unroll
    for (int r = 0; r < 4; ++r) {
      float mx = fmaxf(fmaxf(S[0][r], S[1][r]), fmaxf(S[2][r], S[3][r]));
      mx = fmaxf(mx, __shfl_xor(mx, 1, 64));
      mx = fmaxf(mx, __shfl_xor(mx, 2, 64));
      mx = fmaxf(mx, __shfl_xor(mx, 4, 64));
      mx = fmaxf(mx, __shfl_xor(mx, 8, 64));
      mnew[r] = fmaxf(m_run[r], mx);
      al[r] = __expf(m_run[r] - mnew[r]);
      m_run[r] = mnew[r];
      rs[r] = 0.f;
    }
#pragma unroll
    for (int jn = 0; jn < 4; ++jn)
#pragma unroll
      for (int r = 0; r < 4; ++r) {
        const float p = __expf(S[jn][r] - mnew[r]);
        S[jn][r] = p;
        rs[r] += p;
      }
#pragma unroll
    for (int r = 0; r < 4; ++r) {
      float s = rs[r];
      s += __shfl_xor(s, 1, 64);
      s += __shfl_xor(s, 2, 64);
      s += __shfl_xor(s, 4, 64);
      s += __shfl_xor(s, 8, 64);
      l_run[r] = l_run[r] * al[r] + s;
    }
#pragma unroll
    for (int j = 0; j < 4; ++j) {
      Oa[j][0] *= al[0];
      Oa[j][1] *= al[1];
      Oa[j][2] *= al[2];
      Oa[j][3] *= al[3];
    }
    f16* Pw = Ps + wave * 1024;
#pragma unroll
    for (int jn = 0; jn < 4; ++jn)
#pragma unroll
      for (int r = 0; r < 4; ++r)
        Pw[((jn * 2 + (m16 >> 3)) * 16 + quad * 4 + r) * 8 + (m16 & 7)] =
            (f16)S[jn][r];
    const f16x8 pf0 = *(const f16x8*)&Pw[(quad * 16 + m16) * 8];
    const f16x8 pf1 = *(const f16x8*)&Pw[((4 + quad) * 16 + m16) * 8];
#pragma unroll
    for (int jd = 0; jd < 4; ++jd) {
      const f16x8 vf0 = *(const f16x8*)&Vs[(quad * 64 + jd * 16 + m16) * 8];
      const f16x8 vf1 =
          *(const f16x8*)&Vs[((4 + quad) * 64 + jd * 16 + m16) * 8];
      Oa[jd] = __builtin_amdgcn_mfma_f32_16x16x32_f16(pf0, vf0, Oa[jd], 0, 0, 0);
      Oa[jd] = __builtin_amdgcn_mfma_f32_16x16x32_f16(pf1, vf1, Oa[jd], 0, 0, 0);
    }
    __syncthreads();
  }
#pragma unroll
  for (int jd = 0; jd < 4; ++jd)
#pragma unroll
    for (int r = 0; r < 4; ++r) {
      const float v = Oa[jd][r] / l_run[r];
      const size_t off = (long long)b * sOb +
                         (size_t)(q0 + wave * 16 + quad * 4 + r) * D_ + h * 64 +
                         jd * 16 + m16;
      O[off] = (f16)v;
    }
}

// ---------------------------------------------------------------------------
extern "C" void kernel_launch(void* const* d_in, const int* in_sizes, int n_in,
                              void* d_out, int out_size, void* d_ws,
                              size_t ws_size, hipStream_t stream) {
  const float* x = (const float*)d_in[0];
  const float* coords = (const float*)d_in[1];
  const unsigned char* isctx = (const unsigned char*)d_in[2];
  const float* rope = (const float*)d_in[3];
  const float* ctx_in_w = (const float*)d_in[4];
  const float* ctx_in_b = (const float*)d_in[5];
  const float* ctx_out_w = (const float*)d_in[6];
  const float* ctx_out_b = (const float*)d_in[7];
  const float* tgt_in_w = (const float*)d_in[8];
  const float* tgt_in_b = (const float*)d_in[9];
  const float* tgt_out_w = (const float*)d_in[10];
  const float* tgt_out_b = (const float*)d_in[11];
  float* out = (float*)d_out;

  // ws layout (f16 units): tok 8M | wcat 8M | qkvc 12M | kvt 8M | qt 4M |
  // vt 4M | pos/ipos ints (~92 MB)
  f16* ws = (f16*)d_ws;
  f16* tok = ws;
  f16* wcat = tok + 8388608;
  f16* qkvc = wcat + 8388608;
  f16* kvt = qkvc + 12582912;
  f16* qt = kvt + 8388608;
  f16* vt = qt + 4194304;
  int* pos = (int*)(vt + 4194304);
  int* ipos = pos + B_ * K_;

  partition_kernel<<<B_, 256, 0, stream>>>(isctx, pos, ipos);
  cvt_all<<<8192, 256, 0, stream>>>(ctx_in_w, tgt_in_w, ctx_out_w, tgt_out_w,
                                    wcat);
  rope_kernel<<<B_ * K_, 256, 0, stream>>>(x, coords, rope, ipos, tok);

  // Merged projection: ctx QKV + tgt KV + tgt Q in one dispatch.
  gemm_proj<<<dim3(48, 8, B_), 256, 0, stream>>>(tok, wcat, ctx_in_b,
                                                 tgt_in_b, qkvc, kvt, qt);

  // ctx self-attention (output overwrites tok rows 0..1023)
  vtrans_kernel<<<dim3(16, H_, B_), 256, 0, stream>>>(
      (const ushort_t*)qkvc, (long long)NCTX_ * 3 * D_, 3 * D_, 2 * D_,
      (ushort_t*)vt);
  attn_mfma<<<dim3(16, H_, B_), 256, 0, stream>>>(
      qkvc, (long long)NCTX_ * 3 * D_, 3 * D_, qkvc + D_,
      (long long)NCTX_ * 3 * D_, 3 * D_, vt, tok, (long long)K_ * D_);
  // tgt cross-attention
  vtrans_kernel<<<dim3(16, H_, B_), 256, 0, stream>>>(
      (const ushort_t*)kvt, (long long)NCTX_ * 2 * D_, 2 * D_, D_,
      (ushort_t*)vt);
  attn_mfma<<<dim3(16, H_, B_), 256, 0, stream>>>(
      qt, (long long)NCTX_ * D_, D_, kvt, (long long)NCTX_ * 2 * D_, 2 * D_,
      vt, tok + (size_t)NCTX_ * D_, (long long)K_ * D_);

  // Merged output projections (fp32, scattered to original order)
  gemm_out<<<dim3(8, 8, 2 * B_), 256, 0, stream>>>(
      tok, wcat + 6291456, ctx_out_b, tgt_out_b, ipos, out);
}